// Round 5
// baseline (552.185 us; speedup 1.0000x reference)
//
#include <hip/hip_runtime.h>
#include <hip/hip_bf16.h>

constexpr int kB   = 4;
constexpr int kT   = 2048;
constexpr int kCIN = 2048;
constexpr int kHID = 1024;
constexpr int kEMB = 256;

typedef __bf16 bf16_t;
typedef __bf16 bf16x8 __attribute__((ext_vector_type(8)));
typedef __bf16 bf16x4 __attribute__((ext_vector_type(4)));
typedef float  f32x4  __attribute__((ext_vector_type(4)));

// async global->LDS 16B/lane (LDS dest = wave-uniform base + lane*16)
__device__ __forceinline__ void gll16(const void* g, void* l) {
  auto lp = reinterpret_cast<__attribute__((address_space(3))) uint32_t*>(
      reinterpret_cast<uintptr_t>(l));
  __builtin_amdgcn_global_load_lds(static_cast<const uint32_t*>(g), lp, 16, 0, 0);
}

#define MFMA_BF16 __builtin_amdgcn_mfma_f32_16x16x32_bf16

// ================= 256x256 8-phase double-buffered GEMM core ======================
// C[m,n] (+)= sum_k A[m,k]*B[n,k].  512 thr = 8 waves (2m x 4n), BK=64, Klen%64==0,
// Klen/64 >= 2.  LDS 128 KiB: A dbuf [2][256][64] + B dbuf [2][256][64] bf16.
// Schedule variants tested r1-r4 (pinned 8-phase / free 8-phase / 2-phase): all land
// at 30-33% MfmaUtil -> schedule is NOT the limiter; keep the best (r3, free 8-phase).
// NT=1: non-temporal C-store (stream output past L2/L3 so the write-allocate of
// 68 MB of C does not evict the read panels during the hot loop -> FETCH drops).
// MODE 0: bf16 store; MODE 2: f32 atomicAdd.
template <int MODE, int NT = 0>
__device__ __forceinline__ void gemm256(bf16_t* lds, const bf16_t* A, const bf16_t* B,
                                        void* Cv, int lda, int ldb, int ldc,
                                        int m0, int n0, int Klen, const float* biasN) {
  const int tid  = threadIdx.x;
  const int lane = tid & 63, wv = tid >> 6;
  const int wm = wv & 1, wn = wv >> 1;
  const int lm = lane & 15, q = lane >> 4;
  const int l8 = lane >> 3;
  const int slot = (lane & 7) ^ l8;   // pre-swizzled source 16B-slot

  bf16_t* const sA = lds;
  bf16_t* const sB = lds + 32768;

  // per-thread staging source offsets (elements) for each of the 4 calls/matrix
  int aoff[4], boff[4];
#pragma unroll
  for (int cc = 0; cc < 4; cc++) {
    const int ra = cc * 64 + wv * 8 + l8;                    // lds row this thread fills
    aoff[cc] = ra * lda;                                     // A: identity row map
    const int nb = ((ra >> 5) & 3) * 64 + (ra >> 7) * 32 + (ra & 31);  // B: permuted
    boff[cc] = nb * ldb;
  }
  const bf16_t* const Ab = A + (size_t)m0 * lda + slot * 8;
  const bf16_t* const Bb = B + (size_t)n0 * ldb + slot * 8;

  const int x0 = ((q ^ (lm & 7)) << 3);        // kk=0 swizzled slot (elems)
  const int x1 = (((q + 4) ^ (lm & 7)) << 3);  // kk=1

#define STAGE_A(T, H)                                                         \
  {                                                                           \
    bf16_t* dst_ = sA + (((T) & 1) << 14);                                    \
    const bf16_t* src_ = Ab + ((T) << 6);                                     \
    gll16(src_ + aoff[(H)], dst_ + ((H) << 12) + (wv << 9));                  \
    gll16(src_ + aoff[2 + (H)], dst_ + ((2 + (H)) << 12) + (wv << 9));        \
  }
#define STAGE_B(T, G)                                                         \
  {                                                                           \
    bf16_t* dst_ = sB + (((T) & 1) << 14);                                    \
    const bf16_t* src_ = Bb + ((T) << 6);                                     \
    gll16(src_ + boff[2 * (G)], dst_ + ((2 * (G)) << 12) + (wv << 9));        \
    gll16(src_ + boff[2 * (G) + 1], dst_ + ((2 * (G) + 1) << 12) + (wv << 9));\
  }
#define READ_A(BUF, H)                                                        \
  _Pragma("unroll") for (int i = 0; i < 4; i++) {                             \
    const bf16_t* p_ = (BUF) + ((wm * 128 + (H) * 64 + i * 16 + lm) << 6);    \
    af[i][0] = *(const bf16x8*)(p_ + x0);                                     \
    af[i][1] = *(const bf16x8*)(p_ + x1);                                     \
  }
#define READ_B(BF, BUF, G)                                                    \
  _Pragma("unroll") for (int j2 = 0; j2 < 2; j2++) {                          \
    const bf16_t* p_ = (BUF) + (((G) * 128 + wn * 32 + j2 * 16 + lm) << 6);   \
    BF[j2][0] = *(const bf16x8*)(p_ + x0);                                    \
    BF[j2][1] = *(const bf16x8*)(p_ + x1);                                    \
  }
#define QUAD(H, G, BF)                                                        \
  _Pragma("unroll") for (int i2 = 0; i2 < 4; i2++)                            \
  _Pragma("unroll") for (int j2 = 0; j2 < 2; j2++)                            \
  _Pragma("unroll") for (int kk = 0; kk < 2; kk++)                            \
    acc[(H) * 4 + i2][(G) * 2 + j2] = MFMA_BF16(                              \
        af[i2][kk], BF[j2][kk], acc[(H) * 4 + i2][(G) * 2 + j2], 0, 0, 0);
#define MFMA_OPEN()                                                           \
  asm volatile("s_waitcnt lgkmcnt(0)" ::: "memory");                          \
  __builtin_amdgcn_s_setprio(1);
#define MFMA_CLOSE() __builtin_amdgcn_s_setprio(0);

  f32x4 acc[8][4];
#pragma unroll
  for (int i = 0; i < 8; i++)
#pragma unroll
    for (int j = 0; j < 4; j++)
#pragma unroll
      for (int r = 0; r < 4; r++) acc[i][j][r] = 0.f;

  const int nt = Klen >> 6;

  // prologue: stage tiles 0 and 1 (8 calls each)
  STAGE_A(0, 0) STAGE_B(0, 0) STAGE_B(0, 1) STAGE_A(0, 1)
  STAGE_A(1, 0) STAGE_B(1, 0) STAGE_B(1, 1) STAGE_A(1, 1)
  asm volatile("s_waitcnt vmcnt(8)" ::: "memory");  // oldest 8 = tile0 done
  __builtin_amdgcn_s_barrier();

  bf16x8 af[4][2], bf0[2][2], bf1[2][2];
  for (int t = 0; t < nt; t++) {
    bf16_t* const a = sA + ((t & 1) << 14);
    bf16_t* const b = sB + ((t & 1) << 14);
    const bool pf = (t + 2) < nt;
    // P1: read A-half0 + B-group0 (12 b128); MFMA quadrant (0,0)
    READ_A(a, 0)
    READ_B(bf0, b, 0)
    asm volatile("s_waitcnt lgkmcnt(8)" ::: "memory");  // throttle (12-read phase)
    __builtin_amdgcn_s_barrier();
    MFMA_OPEN()
    QUAD(0, 0, bf0)
    MFMA_CLOSE()
    __builtin_amdgcn_s_barrier();
    // P2: read B-group1 (4 b128); prefetch A-half0(t+2) into region freed at P1
    READ_B(bf1, b, 1)
    if (pf) STAGE_A(t + 2, 0)
    __builtin_amdgcn_s_barrier();
    MFMA_OPEN()
    QUAD(0, 1, bf1)
    MFMA_CLOSE()
    __builtin_amdgcn_s_barrier();
    // P3: read A-half1 (8 b128); prefetch B-group0(t+2) (freed at P1)
    READ_A(a, 1)
    if (pf) STAGE_B(t + 2, 0)
    __builtin_amdgcn_s_barrier();
    MFMA_OPEN()
    QUAD(1, 1, bf1)
    MFMA_CLOSE()
    __builtin_amdgcn_s_barrier();
    // P4: prefetch B-group1(t+2) (freed P2) + A-half1(t+2) (freed P3); reg-only MFMA
    if (pf) { STAGE_B(t + 2, 1) STAGE_A(t + 2, 1) }
    __builtin_amdgcn_s_barrier();
    __builtin_amdgcn_s_setprio(1);
    QUAD(1, 0, bf0)
    __builtin_amdgcn_s_setprio(0);
    if (pf)
      asm volatile("s_waitcnt vmcnt(8)" ::: "memory");   // tile t+1 fully landed
    else if (t + 1 < nt)
      asm volatile("s_waitcnt vmcnt(0)" ::: "memory");   // drain for last tile
    __builtin_amdgcn_s_barrier();
  }

  // epilogue: C/D layout col=lane&15, row=(lane>>4)*4+reg
#pragma unroll
  for (int i = 0; i < 8; i++) {
    const int gm = m0 + wm * 128 + (i >> 2) * 64 + (i & 3) * 16 + q * 4;
#pragma unroll
    for (int j = 0; j < 4; j++) {
      const int gn = n0 + wn * 64 + j * 16 + lm;
      const float bn_ = biasN ? biasN[gn] : 0.f;
#pragma unroll
      for (int r = 0; r < 4; r++) {
        const float v = acc[i][j][r] + bn_;
        const size_t idx = (size_t)(gm + r) * ldc + gn;
        if (MODE == 0) {
          if (NT) {
            union { bf16_t h; unsigned short u; } cv; cv.h = (bf16_t)v;
            __builtin_nontemporal_store(cv.u, (unsigned short*)Cv + idx);
          } else {
            ((bf16_t*)Cv)[idx] = (bf16_t)v;
          }
        } else {
          atomicAdd(&((float*)Cv)[idx], v);
        }
      }
    }
  }
#undef STAGE_A
#undef STAGE_B
#undef READ_A
#undef READ_B
#undef QUAD
#undef MFMA_OPEN
#undef MFMA_CLOSE
}

// ================= dispatch 1: prep (casts + wwT + biases) + zero(out) ============
__global__ __launch_bounds__(256) void k_prep(const float* __restrict__ x,
                                              const float* __restrict__ th,
                                              const float* __restrict__ ph,
                                              const float* __restrict__ g,
                                              const float* __restrict__ emb,
                                              const float* __restrict__ w_w,
                                              const float* __restrict__ w_b,
                                              const float* __restrict__ emb_b,
                                              const float* __restrict__ tb,
                                              const float* __restrict__ pb,
                                              const float* __restrict__ gb,
                                              bf16_t* __restrict__ xbf,
                                              bf16_t* __restrict__ wqkv,
                                              bf16_t* __restrict__ embbf,
                                              bf16_t* __restrict__ wwT,
                                              float* __restrict__ biase,
                                              float* __restrict__ bqkv,
                                              float* __restrict__ out) {
  __shared__ float tile[64 * 66];
  const int b = blockIdx.x;
  if (b < 23040) {  // casts
    const float* in; bf16_t* o; long i;
    if (b < 16384)      { in = x;   o = xbf;                            i = (long)b * 256 + threadIdx.x; }
    else if (b < 18432) { in = th;  o = wqkv;                           i = (long)(b - 16384) * 256 + threadIdx.x; }
    else if (b < 20480) { in = ph;  o = wqkv + (size_t)kHID * kCIN;     i = (long)(b - 18432) * 256 + threadIdx.x; }
    else if (b < 22528) { in = g;   o = wqkv + (size_t)2 * kHID * kCIN; i = (long)(b - 20480) * 256 + threadIdx.x; }
    else                { in = emb; o = embbf;                          i = (long)(b - 22528) * 256 + threadIdx.x; }
    float4 v = ((const float4*)in)[i];
    bf16x4 ov;
    ov[0] = (bf16_t)v.x; ov[1] = (bf16_t)v.y; ov[2] = (bf16_t)v.z; ov[3] = (bf16_t)v.w;
    ((bf16x4*)o)[i] = ov;
  } else if (b < 23552) {  // w_w (CIN,HID) -> wwT (HID,CIN), 64x64 tiles
    int j = b - 23040;
    int h0 = (j & 15) * 64, c0 = (j >> 4) * 64;
#pragma unroll
    for (int k = 0; k < 16; k++) {
      int e = k * 256 + threadIdx.x;
      int r = e >> 6, c = e & 63;
      tile[r * 66 + c] = w_w[(size_t)(c0 + r) * kHID + h0 + c];
    }
    __syncthreads();
#pragma unroll
    for (int k = 0; k < 16; k++) {
      int e = k * 256 + threadIdx.x;
      int r = e >> 6, c = e & 63;
      wwT[(size_t)(h0 + r) * kCIN + c0 + c] = (bf16_t)tile[c * 66 + r];
    }
  } else if (b < 23808) {  // bias_e
    int e = b - 23552;
    float acc = 0.f;
    for (int c = threadIdx.x; c < kCIN; c += 256)
      acc += emb[(size_t)e * kCIN + c] * w_b[c];
#pragma unroll
    for (int o = 32; o > 0; o >>= 1) acc += __shfl_xor(acc, o, 64);
    __syncthreads();
    if ((threadIdx.x & 63) == 0) tile[threadIdx.x >> 6] = acc;
    __syncthreads();
    if (threadIdx.x == 0) biase[e] = tile[0] + tile[1] + tile[2] + tile[3] + emb_b[e];
  } else if (b < 23820) {  // concat biases -> bqkv[3072]
    int i = (b - 23808) * 256 + threadIdx.x;
    if (i < 3072)
      bqkv[i] = i < 1024 ? tb[i] : (i < 2048 ? pb[i - 1024] : gb[i - 2048]);
  } else {  // zero d_out (2M f32 = 524288 float4)
    long i = (long)(b - 23820) * 256 + threadIdx.x;
    ((float4*)out)[i] = make_float4(0.f, 0.f, 0.f, 0.f);
  }
}

// ========== dispatch 2: QKV(384) + S1-tri(144) + M(4) = 532 uniform blocks ========
// Linear blockIdx (r4 lesson: default i%8 XCD round-robin already yields a compact
// 4bm x 8bn rectangle per XCD; chunked swizzle blew up the A working set, FETCH +28%).
__global__ __launch_bounds__(512, 2) void k_mega1(const bf16_t* __restrict__ xbf,
                                                  const bf16_t* __restrict__ wqkv,
                                                  const bf16_t* __restrict__ embbf,
                                                  const bf16_t* __restrict__ wwT,
                                                  bf16_t* __restrict__ xtphi,
                                                  bf16_t* __restrict__ S1,
                                                  bf16_t* __restrict__ Mbf,
                                                  const float* __restrict__ bqkv) {
  __shared__ bf16_t lds[65536];  // 128 KiB
  const int tile = blockIdx.x;
  if (tile < 384) {  // xtphi = x @ wqkv^T + bqkv (8192 x 3072, K=2048)
    const int bm = tile & 31, bn = tile >> 5;
    gemm256<0, 1>(lds, xbf, wqkv, xtphi, 2048, 2048, 3072,
                  bm * 256, bn * 256, 2048, bqkv);
  } else if (tile < 528) {  // S1[z] = x[z] @ x[z]^T, upper triangular 256-tiles
    int s = tile - 384;
    const int z = s / 36;
    int tt = s % 36, rr = 0;
    while (tt >= 8 - rr) { tt -= 8 - rr; rr++; }
    const bf16_t* Az = xbf + (size_t)z * kT * kCIN;
    gemm256<0, 1>(lds, Az, Az, S1 + (size_t)z * kT * kT, 2048, 2048, 2048,
                  rr * 256, (rr + tt) * 256, 2048, nullptr);
  } else {  // M = emb @ w_w (256 x 1024, K=2048)
    const int m = tile - 528;
    gemm256<0, 1>(lds, embbf, wwT, Mbf, 2048, 2048, 1024, 0, m * 256, 2048, nullptr);
  }
}

// ================= dispatch 3: S2 (256 blocks = exactly 1 round) ==================
__global__ __launch_bounds__(512, 2) void k_gemm2(const bf16_t* __restrict__ xtphi,
                                                  bf16_t* __restrict__ S2) {
  __shared__ bf16_t lds[65536];
  const int bid = blockIdx.x;
  const int bm = bid & 7, bn = (bid >> 3) & 7, z = bid >> 6;
  const bf16_t* base = xtphi + (size_t)z * kT * 3072;
  gemm256<0, 1>(lds, base + 1024, base, S2 + (size_t)z * kT * kT, 3072, 3072, 2048,
                bm * 256, bn * 256, 1024, nullptr);
}

// ====== dispatch 4: mirror S1 (1984) + xg-transpose (2048), 256-thread blocks =====
__global__ __launch_bounds__(256) void k_util(bf16_t* __restrict__ S1,
                                              const bf16_t* __restrict__ xtphi,
                                              bf16_t* __restrict__ xgT) {
  __shared__ bf16_t tile[64 * 66];
  const int bid = blockIdx.x;
  const size_t T2 = (size_t)kT * kT;
  if (bid < 1984) {  // mirror S1 upper -> lower (64x64 tiles, p>q)
    int z = bid / 496, t = bid % 496, qq = 0;
    while (t >= 31 - qq) { t -= 31 - qq; qq++; }
    int p = qq + 1 + t;
    const size_t base = (size_t)z * T2;
#pragma unroll
    for (int k = 0; k < 16; k++) {
      int e = k * 256 + threadIdx.x;
      int r = e >> 6, c = e & 63;
      tile[r * 66 + c] = S1[base + (size_t)(qq * 64 + r) * kT + p * 64 + c];
    }
    __syncthreads();
#pragma unroll
    for (int k = 0; k < 16; k++) {
      int e = k * 256 + threadIdx.x;
      int r = e >> 6, c = e & 63;
      S1[base + (size_t)(p * 64 + r) * kT + qq * 64 + c] = tile[c * 66 + r];
    }
  } else {  // xgT[z](h,t) from xg slice of xtphi
    int j = bid - 1984;
    int hb = j & 15, tb2 = (j >> 4) & 31, z = j >> 9;
#pragma unroll
    for (int k = 0; k < 16; k++) {
      int e = k * 256 + threadIdx.x;
      int r = e >> 6, c = e & 63;  // r: t, c: h
      tile[r * 66 + c] = xtphi[(size_t)(z * kT + tb2 * 64 + r) * 3072 + 2048 + hb * 64 + c];
    }
    __syncthreads();
#pragma unroll
    for (int k = 0; k < 16; k++) {
      int e = k * 256 + threadIdx.x;
      int r = e >> 6, c = e & 63;  // r: h, c: t
      xgT[(size_t)z * kHID * kT + (size_t)(hb * 64 + r) * kT + tb2 * 64 + c] = tile[c * 66 + r];
    }
  }
}

// ============ dispatch 5: moca — wave-per-row, register-resident ==================
// 4 rows/block (1 wave each). 32 f32 x 2 per lane; shuffle-only reductions; no LDS,
// no __syncthreads (was 24 per block). Grid (kT/4, kB).
__global__ __launch_bounds__(256) void k_moca(const bf16_t* __restrict__ S1,
                                              const bf16_t* __restrict__ S2,
                                              bf16_t* __restrict__ dst,
                                              const float* __restrict__ rou_w,
                                              const float* __restrict__ rou_b) {
  const int wv = threadIdx.x >> 6, lane = threadIdx.x & 63;
  const int t = blockIdx.x * 4 + wv, b = blockIdx.y;
  const size_t T2 = (size_t)kT * kT;
  const bf16_t* src = (b < 2) ? S1 : S2;
  const int pb = (b < 2) ? 2 * b : 2 * (b - 2);
  const bf16_t* rA = src + (size_t)pb * T2 + (size_t)t * kT;
  const bf16_t* rB = rA + T2;

  float va[32], vb[32];
#pragma unroll
  for (int c = 0; c < 4; c++) {
    bf16x8 a  = *(const bf16x8*)(rA + c * 512 + lane * 8);
    bf16x8 bb = *(const bf16x8*)(rB + c * 512 + lane * 8);
#pragma unroll
    for (int k = 0; k < 8; k++) { va[c * 8 + k] = (float)a[k]; vb[c * 8 + k] = (float)bb[k]; }
  }
  auto wmax = [](float v) {
#pragma unroll
    for (int o = 32; o > 0; o >>= 1) v = fmaxf(v, __shfl_xor(v, o, 64));
    return v;
  };
  auto wsum = [](float v) {
#pragma unroll
    for (int o = 32; o > 0; o >>= 1) v += __shfl_xor(v, o, 64);
    return v;
  };

  float m = -1e30f, s;
#pragma unroll
  for (int j = 0; j < 32; j++) m = fmaxf(m, va[j]);
  m = wmax(m); s = 0.f;
#pragma unroll
  for (int j = 0; j < 32; j++) { va[j] = __expf(va[j] - m); s += va[j]; }
  const float invA = 1.f / wsum(s);

  m = -1e30f;
#pragma unroll
  for (int j = 0; j < 32; j++) m = fmaxf(m, vb[j]);
  m = wmax(m); s = 0.f;
#pragma unroll
  for (int j = 0; j < 32; j++) { vb[j] = __expf(vb[j] - m); s += vb[j]; }
  const float invB = 1.f / wsum(s);

  const float r0 = rou_w[0], r1 = rou_w[1], rb2 = rou_b[0];
#pragma unroll
  for (int j = 0; j < 32; j++) va[j] = r0 * va[j] * invA + r1 * vb[j] * invB + rb2;

  m = -1e30f;
#pragma unroll
  for (int j = 0; j < 32; j++) m = fmaxf(m, va[j]);
  m = wmax(m); s = 0.f;
#pragma unroll
  for (int j = 0; j < 32; j++) { va[j] = __expf(va[j] - m); s += va[j]; }
  const float invC = 1.f / wsum(s);

  bf16_t* o = dst + (size_t)b * T2 + (size_t)t * kT;
#pragma unroll
  for (int c = 0; c < 4; c++) {
    bf16x8 ov;
#pragma unroll
    for (int k = 0; k < 8; k++) ov[k] = (bf16_t)(va[c * 8 + k] * invC);
    *(bf16x8*)(o + c * 512 + lane * 8) = ov;
  }
}

// ================= dispatch 6: mocab -> mocaT (batched TxT transpose) =============
__global__ __launch_bounds__(256) void k_mocaT(const bf16_t* __restrict__ in,
                                               bf16_t* __restrict__ out) {
  __shared__ bf16_t tile[64 * 66];
  size_t base = (size_t)blockIdx.z * kT * kT;
  int r0 = blockIdx.y * 64, c0 = blockIdx.x * 64;
#pragma unroll
  for (int k = 0; k < 16; k++) {
    int e = k * 256 + threadIdx.x;
    int r = e >> 6, c = e & 63;
    tile[r * 66 + c] = in[base + (size_t)(r0 + r) * kT + c0 + c];
  }
  __syncthreads();
#pragma unroll
  for (int k = 0; k < 16; k++) {
    int e = k * 256 + threadIdx.x;
    int r = e >> 6, c = e & 63;
    out[base + (size_t)(c0 + r) * kT + r0 + c] = tile[c * 66 + r];
  }
}

// ====== dispatch 7: yT GEMM (128) + x@emb^T split-K4 atomic (128) = 256 blocks ====
__global__ __launch_bounds__(512, 2) void k_tail1(const bf16_t* __restrict__ mocaT,
                                                  const bf16_t* __restrict__ xgT,
                                                  bf16_t* __restrict__ yT,
                                                  const bf16_t* __restrict__ xbf,
                                                  const bf16_t* __restrict__ embbf,
                                                  float* __restrict__ out,
                                                  const float* __restrict__ biase) {
  __shared__ bf16_t lds[65536];
  const int bid = blockIdx.x;
  if (bid < 128) {  // yT[z] = mocaT[z] @ xgT[z]^T (2048 x 1024, K=2048)
    const int bm = bid & 7, bn = (bid >> 3) & 3, z = bid >> 5;
    gemm256<0>(lds, mocaT + (size_t)z * kT * kT, xgT + (size_t)z * kHID * kT,
               yT + (size_t)z * kT * kHID, 2048, 2048, 1024,
               bm * 256, bn * 256, 2048, nullptr);
  } else {  // out += x @ emb^T (K=512 slices), + biase on slice 0
    const int r = bid - 128;
    const int bm = r & 31, ks = r >> 5;
    gemm256<2>(lds, xbf + ks * 512, embbf + ks * 512, out, 2048, 2048, 256,
               bm * 256, 0, 512, ks == 0 ? biase : nullptr);
  }
}

// ================= dispatch 8: out += yT @ M^T split-K4 atomic (128) ==============
__global__ __launch_bounds__(512, 2) void k_tail2(const bf16_t* __restrict__ yT,
                                                  const bf16_t* __restrict__ Mbf,
                                                  float* __restrict__ out) {
  __shared__ bf16_t lds[65536];
  const int bid = blockIdx.x;
  const int bm = bid & 31, ks = bid >> 5;
  gemm256<2>(lds, yT + ks * 256, Mbf + ks * 256, out, 1024, 1024, 256,
             bm * 256, 0, 256, nullptr);
}

extern "C" void kernel_launch(void* const* d_in, const int* in_sizes, int n_in,
                              void* d_out, int out_size, void* d_ws, size_t ws_size,
                              hipStream_t stream) {
  const float* x       = (const float*)d_in[0];
  const float* theta_w = (const float*)d_in[1];
  const float* theta_b = (const float*)d_in[2];
  const float* phi_w   = (const float*)d_in[3];
  const float* phi_b   = (const float*)d_in[4];
  const float* g_w     = (const float*)d_in[5];
  const float* g_b     = (const float*)d_in[6];
  const float* rou_w   = (const float*)d_in[7];
  const float* rou_b   = (const float*)d_in[8];
  const float* w_w     = (const float*)d_in[9];
  const float* w_b     = (const float*)d_in[10];
  const float* emb_w   = (const float*)d_in[11];
  const float* emb_b   = (const float*)d_in[12];
  float* out = (float*)d_out;

  char* ws = (char*)d_ws;
  size_t off = 0;
  auto alloc = [&](size_t bytes) -> char* {
    off = (off + 255) & ~(size_t)255;
    char* p = ws + off;
    off += bytes;
    return p;
  };

  const size_t BT = (size_t)kB * kT;   // 8192
  const size_t T2 = (size_t)kT * kT;   // 4M

  bf16_t* xbf   = (bf16_t*)alloc(BT * kCIN * 2);               // 33.5 MB
  bf16_t* wqkv  = (bf16_t*)alloc((size_t)3 * kHID * kCIN * 2); // 12.6 MB
  bf16_t* embbf = (bf16_t*)alloc((size_t)kEMB * kCIN * 2);     // 1.0 MB
  bf16_t* wwT   = (bf16_t*)alloc((size_t)kHID * kCIN * 2);     // 4.2 MB
  bf16_t* xtphi = (bf16_t*)alloc(BT * 3072 * 2);               // 50.3 MB [xt|xphi|xg]
  bf16_t* xgT   = (bf16_t*)alloc((size_t)kB * kHID * kT * 2);  // 16.8 MB
  bf16_t* mocab = (bf16_t*)alloc((size_t)kB * T2 * 2);         // 33.5 MB
  bf16_t* Mbf   = (bf16_t*)alloc((size_t)kEMB * kHID * 2);     // 0.5 MB
  float*  biase = (float*)alloc((size_t)kEMB * 4);
  float*  bqkv  = (float*)alloc((size_t)3072 * 4);
  bf16_t* S1    = (bf16_t*)alloc((size_t)kB * T2 * 2);         // 33.5 MB
  bf16_t* S2    = (bf16_t*)alloc((size_t)kB * T2 * 2);         // 33.5 MB
  // aliases over dead regions:
  bf16_t* mocaT = (bf16_t*)xtphi;  // xtphi dead after k_gemm2 + k_util(xgT)
  bf16_t* yT    = (bf16_t*)S2;     // S2 dead after k_moca (16.8 <= 33.5)

  // 1: prep (casts + wwT + bias_e + bqkv + zero(out))
  k_prep<<<dim3(25868), 256, 0, stream>>>(x, theta_w, phi_w, g_w, emb_w, w_w, w_b,
                                          emb_b, theta_b, phi_b, g_b,
                                          xbf, wqkv, embbf, wwT, biase, bqkv, out);
  // 2: QKV + S1-triangular + M (532 uniform K=2048 tiles)
  k_mega1<<<dim3(532), 512, 0, stream>>>(xbf, wqkv, embbf, wwT, xtphi, S1, Mbf, bqkv);
  // 3: S2
  k_gemm2<<<dim3(256), 512, 0, stream>>>(xtphi, S2);
  // 4: mirror(S1) + xgT
  k_util<<<dim3(4032), 256, 0, stream>>>(S1, xtphi, xgT);
  // 5: moca (both passes, wave-per-row)
  k_moca<<<dim3(kT / 4, kB), 256, 0, stream>>>(S1, S2, mocab, rou_w, rou_b);
  // 6: mocaT (overwrites dead xtphi)
  k_mocaT<<<dim3(32, 32, kB), 256, 0, stream>>>(mocab, mocaT);
  // 7: yT GEMM (over dead S2) + x@emb^T split-K atomic
  k_tail1<<<dim3(256), 512, 0, stream>>>(mocaT, xgT, yT, xbf, embbf, out, biase);
  // 8: out += yT @ M^T split-K atomic
  k_tail2<<<dim3(128), 512, 0, stream>>>(yT, Mbf, out);
}

// Round 6
// 456.223 us; speedup vs baseline: 1.2103x; 1.2103x over previous
//
#include <hip/hip_runtime.h>
#include <hip/hip_bf16.h>

constexpr int kB   = 4;
constexpr int kT   = 2048;
constexpr int kCIN = 2048;
constexpr int kHID = 1024;
constexpr int kEMB = 256;

typedef __bf16 bf16_t;
typedef __bf16 bf16x8 __attribute__((ext_vector_type(8)));
typedef __bf16 bf16x4 __attribute__((ext_vector_type(4)));
typedef float  f32x4  __attribute__((ext_vector_type(4)));

// async global->LDS 16B/lane (LDS dest = wave-uniform base + lane*16)
__device__ __forceinline__ void gll16(const void* g, void* l) {
  auto lp = reinterpret_cast<__attribute__((address_space(3))) uint32_t*>(
      reinterpret_cast<uintptr_t>(l));
  __builtin_amdgcn_global_load_lds(static_cast<const uint32_t*>(g), lp, 16, 0, 0);
}

#define MFMA_BF16 __builtin_amdgcn_mfma_f32_16x16x32_bf16

// ================= 256x256 8-phase double-buffered GEMM core ======================
// C[m,n] (+)= sum_k A[m,k]*B[n,k].  512 thr = 8 waves (2m x 4n), BK=64, Klen%64==0,
// Klen/64 >= 4.  LDS 128 KiB: A dbuf [2][256][64] + B dbuf [2][256][64] bf16.
// r1-r5 lessons baked in: schedule variants all equivalent (keep r3 free 8-phase);
// NO non-temporal stores (r5: per-lane 2B NT stores doubled WRITE_SIZE); the real
// limiter at dispatch level is round quantization (r5 occupancy analysis).
// MODE 0: bf16 store; MODE 1: f32 plain store; MODE 2: f32 atomicAdd.
template <int MODE>
__device__ __forceinline__ void gemm256(bf16_t* lds, const bf16_t* A, const bf16_t* B,
                                        void* Cv, int lda, int ldb, int ldc,
                                        int m0, int n0, int Klen, const float* biasN) {
  const int tid  = threadIdx.x;
  const int lane = tid & 63, wv = tid >> 6;
  const int wm = wv & 1, wn = wv >> 1;
  const int lm = lane & 15, q = lane >> 4;
  const int l8 = lane >> 3;
  const int slot = (lane & 7) ^ l8;   // pre-swizzled source 16B-slot

  bf16_t* const sA = lds;
  bf16_t* const sB = lds + 32768;

  // per-thread staging source offsets (elements) for each of the 4 calls/matrix
  int aoff[4], boff[4];
#pragma unroll
  for (int cc = 0; cc < 4; cc++) {
    const int ra = cc * 64 + wv * 8 + l8;                    // lds row this thread fills
    aoff[cc] = ra * lda;                                     // A: identity row map
    const int nb = ((ra >> 5) & 3) * 64 + (ra >> 7) * 32 + (ra & 31);  // B: permuted
    boff[cc] = nb * ldb;
  }
  const bf16_t* const Ab = A + (size_t)m0 * lda + slot * 8;
  const bf16_t* const Bb = B + (size_t)n0 * ldb + slot * 8;

  const int x0 = ((q ^ (lm & 7)) << 3);        // kk=0 swizzled slot (elems)
  const int x1 = (((q + 4) ^ (lm & 7)) << 3);  // kk=1

#define STAGE_A(T, H)                                                         \
  {                                                                           \
    bf16_t* dst_ = sA + (((T) & 1) << 14);                                    \
    const bf16_t* src_ = Ab + ((T) << 6);                                     \
    gll16(src_ + aoff[(H)], dst_ + ((H) << 12) + (wv << 9));                  \
    gll16(src_ + aoff[2 + (H)], dst_ + ((2 + (H)) << 12) + (wv << 9));        \
  }
#define STAGE_B(T, G)                                                         \
  {                                                                           \
    bf16_t* dst_ = sB + (((T) & 1) << 14);                                    \
    const bf16_t* src_ = Bb + ((T) << 6);                                     \
    gll16(src_ + boff[2 * (G)], dst_ + ((2 * (G)) << 12) + (wv << 9));        \
    gll16(src_ + boff[2 * (G) + 1], dst_ + ((2 * (G) + 1) << 12) + (wv << 9));\
  }
#define READ_A(BUF, H)                                                        \
  _Pragma("unroll") for (int i = 0; i < 4; i++) {                             \
    const bf16_t* p_ = (BUF) + ((wm * 128 + (H) * 64 + i * 16 + lm) << 6);    \
    af[i][0] = *(const bf16x8*)(p_ + x0);                                     \
    af[i][1] = *(const bf16x8*)(p_ + x1);                                     \
  }
#define READ_B(BF, BUF, G)                                                    \
  _Pragma("unroll") for (int j2 = 0; j2 < 2; j2++) {                          \
    const bf16_t* p_ = (BUF) + (((G) * 128 + wn * 32 + j2 * 16 + lm) << 6);   \
    BF[j2][0] = *(const bf16x8*)(p_ + x0);                                    \
    BF[j2][1] = *(const bf16x8*)(p_ + x1);                                    \
  }
#define QUAD(H, G, BF)                                                        \
  _Pragma("unroll") for (int i2 = 0; i2 < 4; i2++)                            \
  _Pragma("unroll") for (int j2 = 0; j2 < 2; j2++)                            \
  _Pragma("unroll") for (int kk = 0; kk < 2; kk++)                            \
    acc[(H) * 4 + i2][(G) * 2 + j2] = MFMA_BF16(                              \
        af[i2][kk], BF[j2][kk], acc[(H) * 4 + i2][(G) * 2 + j2], 0, 0, 0);
#define MFMA_OPEN()                                                           \
  asm volatile("s_waitcnt lgkmcnt(0)" ::: "memory");                          \
  __builtin_amdgcn_s_setprio(1);
#define MFMA_CLOSE() __builtin_amdgcn_s_setprio(0);

  f32x4 acc[8][4];
#pragma unroll
  for (int i = 0; i < 8; i++)
#pragma unroll
    for (int j = 0; j < 4; j++)
#pragma unroll
      for (int r = 0; r < 4; r++) acc[i][j][r] = 0.f;

  const int nt = Klen >> 6;

  // prologue: stage tiles 0 and 1 (8 calls each)
  STAGE_A(0, 0) STAGE_B(0, 0) STAGE_B(0, 1) STAGE_A(0, 1)
  STAGE_A(1, 0) STAGE_B(1, 0) STAGE_B(1, 1) STAGE_A(1, 1)
  asm volatile("s_waitcnt vmcnt(8)" ::: "memory");  // oldest 8 = tile0 done
  __builtin_amdgcn_s_barrier();

  bf16x8 af[4][2], bf0[2][2], bf1[2][2];
  for (int t = 0; t < nt; t++) {
    bf16_t* const a = sA + ((t & 1) << 14);
    bf16_t* const b = sB + ((t & 1) << 14);
    const bool pf = (t + 2) < nt;
    // P1: read A-half0 + B-group0 (12 b128); MFMA quadrant (0,0)
    READ_A(a, 0)
    READ_B(bf0, b, 0)
    asm volatile("s_waitcnt lgkmcnt(8)" ::: "memory");  // throttle (12-read phase)
    __builtin_amdgcn_s_barrier();
    MFMA_OPEN()
    QUAD(0, 0, bf0)
    MFMA_CLOSE()
    __builtin_amdgcn_s_barrier();
    // P2: read B-group1 (4 b128); prefetch A-half0(t+2) into region freed at P1
    READ_B(bf1, b, 1)
    if (pf) STAGE_A(t + 2, 0)
    __builtin_amdgcn_s_barrier();
    MFMA_OPEN()
    QUAD(0, 1, bf1)
    MFMA_CLOSE()
    __builtin_amdgcn_s_barrier();
    // P3: read A-half1 (8 b128); prefetch B-group0(t+2) (freed at P1)
    READ_A(a, 1)
    if (pf) STAGE_B(t + 2, 0)
    __builtin_amdgcn_s_barrier();
    MFMA_OPEN()
    QUAD(1, 1, bf1)
    MFMA_CLOSE()
    __builtin_amdgcn_s_barrier();
    // P4: prefetch B-group1(t+2) (freed P2) + A-half1(t+2) (freed P3); reg-only MFMA
    if (pf) { STAGE_B(t + 2, 1) STAGE_A(t + 2, 1) }
    __builtin_amdgcn_s_barrier();
    __builtin_amdgcn_s_setprio(1);
    QUAD(1, 0, bf0)
    __builtin_amdgcn_s_setprio(0);
    if (pf)
      asm volatile("s_waitcnt vmcnt(8)" ::: "memory");   // tile t+1 fully landed
    else if (t + 1 < nt)
      asm volatile("s_waitcnt vmcnt(0)" ::: "memory");   // drain for last tile
    __builtin_amdgcn_s_barrier();
  }

  // epilogue: C/D layout col=lane&15, row=(lane>>4)*4+reg
#pragma unroll
  for (int i = 0; i < 8; i++) {
    const int gm = m0 + wm * 128 + (i >> 2) * 64 + (i & 3) * 16 + q * 4;
#pragma unroll
    for (int j = 0; j < 4; j++) {
      const int gn = n0 + wn * 64 + j * 16 + lm;
      const float bn_ = biasN ? biasN[gn] : 0.f;
#pragma unroll
      for (int r = 0; r < 4; r++) {
        const float v = acc[i][j][r] + bn_;
        const size_t idx = (size_t)(gm + r) * ldc + gn;
        if (MODE == 0)      ((bf16_t*)Cv)[idx] = (bf16_t)v;
        else if (MODE == 1) ((float*)Cv)[idx] = v;
        else                atomicAdd(&((float*)Cv)[idx], v);
      }
    }
  }
#undef STAGE_A
#undef STAGE_B
#undef READ_A
#undef READ_B
#undef QUAD
#undef MFMA_OPEN
#undef MFMA_CLOSE
}

// ================= dispatch 1: prep (casts + wwT + biases) + zero(out) ============
__global__ __launch_bounds__(256) void k_prep(const float* __restrict__ x,
                                              const float* __restrict__ th,
                                              const float* __restrict__ ph,
                                              const float* __restrict__ g,
                                              const float* __restrict__ emb,
                                              const float* __restrict__ w_w,
                                              const float* __restrict__ w_b,
                                              const float* __restrict__ emb_b,
                                              const float* __restrict__ tb,
                                              const float* __restrict__ pb,
                                              const float* __restrict__ gb,
                                              bf16_t* __restrict__ xbf,
                                              bf16_t* __restrict__ wqkv,
                                              bf16_t* __restrict__ embbf,
                                              bf16_t* __restrict__ wwT,
                                              float* __restrict__ biase,
                                              float* __restrict__ bqkv,
                                              float* __restrict__ out) {
  __shared__ float tile[64 * 66];
  const int b = blockIdx.x;
  if (b < 23040) {  // casts
    const float* in; bf16_t* o; long i;
    if (b < 16384)      { in = x;   o = xbf;                            i = (long)b * 256 + threadIdx.x; }
    else if (b < 18432) { in = th;  o = wqkv;                           i = (long)(b - 16384) * 256 + threadIdx.x; }
    else if (b < 20480) { in = ph;  o = wqkv + (size_t)kHID * kCIN;     i = (long)(b - 18432) * 256 + threadIdx.x; }
    else if (b < 22528) { in = g;   o = wqkv + (size_t)2 * kHID * kCIN; i = (long)(b - 20480) * 256 + threadIdx.x; }
    else                { in = emb; o = embbf;                          i = (long)(b - 22528) * 256 + threadIdx.x; }
    float4 v = ((const float4*)in)[i];
    bf16x4 ov;
    ov[0] = (bf16_t)v.x; ov[1] = (bf16_t)v.y; ov[2] = (bf16_t)v.z; ov[3] = (bf16_t)v.w;
    ((bf16x4*)o)[i] = ov;
  } else if (b < 23552) {  // w_w (CIN,HID) -> wwT (HID,CIN), 64x64 tiles
    int j = b - 23040;
    int h0 = (j & 15) * 64, c0 = (j >> 4) * 64;
#pragma unroll
    for (int k = 0; k < 16; k++) {
      int e = k * 256 + threadIdx.x;
      int r = e >> 6, c = e & 63;
      tile[r * 66 + c] = w_w[(size_t)(c0 + r) * kHID + h0 + c];
    }
    __syncthreads();
#pragma unroll
    for (int k = 0; k < 16; k++) {
      int e = k * 256 + threadIdx.x;
      int r = e >> 6, c = e & 63;
      wwT[(size_t)(h0 + r) * kCIN + c0 + c] = (bf16_t)tile[c * 66 + r];
    }
  } else if (b < 23808) {  // bias_e
    int e = b - 23552;
    float acc = 0.f;
    for (int c = threadIdx.x; c < kCIN; c += 256)
      acc += emb[(size_t)e * kCIN + c] * w_b[c];
#pragma unroll
    for (int o = 32; o > 0; o >>= 1) acc += __shfl_xor(acc, o, 64);
    __syncthreads();
    if ((threadIdx.x & 63) == 0) tile[threadIdx.x >> 6] = acc;
    __syncthreads();
    if (threadIdx.x == 0) biase[e] = tile[0] + tile[1] + tile[2] + tile[3] + emb_b[e];
  } else if (b < 23820) {  // concat biases -> bqkv[3072]
    int i = (b - 23808) * 256 + threadIdx.x;
    if (i < 3072)
      bqkv[i] = i < 1024 ? tb[i] : (i < 2048 ? pb[i - 1024] : gb[i - 2048]);
  } else {  // zero d_out (2M f32 = 524288 float4)
    long i = (long)(b - 23820) * 256 + threadIdx.x;
    ((float4*)out)[i] = make_float4(0.f, 0.f, 0.f, 0.f);
  }
}

// ====== dispatch 2: 512 full jobs (2 exact rounds) + 80 quarter split-K jobs ======
// fulls: 384 xtphi + 124 S1-tri + 4 M.  quarters: last 20 S1-tri tiles, each as
// 4 K=512 jobs writing f32 PARTIAL tiles to S1f (summed+cast in dispatch 3).
// This removes the 20-block third round (532 jobs = 3 rounds; 69% util) -> 72u
// makespan instead of 96u.
__global__ __launch_bounds__(512, 2) void k_mega1(const bf16_t* __restrict__ xbf,
                                                  const bf16_t* __restrict__ wqkv,
                                                  const bf16_t* __restrict__ embbf,
                                                  const bf16_t* __restrict__ wwT,
                                                  bf16_t* __restrict__ xtphi,
                                                  bf16_t* __restrict__ S1,
                                                  bf16_t* __restrict__ Mbf,
                                                  const float* __restrict__ bqkv,
                                                  float* __restrict__ S1f) {
  __shared__ bf16_t lds[65536];  // 128 KiB
  const int bid = blockIdx.x;
  if (bid < 384) {  // xtphi = x @ wqkv^T + bqkv (8192 x 3072, K=2048)
    const int bm = bid & 31, bn = bid >> 5;
    gemm256<0>(lds, xbf, wqkv, xtphi, 2048, 2048, 3072,
               bm * 256, bn * 256, 2048, bqkv);
  } else if (bid < 508) {  // S1 full tiles: s = 0..123
    int s = bid - 384;
    const int z = s / 36;
    int tt = s % 36, rr = 0;
    while (tt >= 8 - rr) { tt -= 8 - rr; rr++; }
    const bf16_t* Az = xbf + (size_t)z * kT * kCIN;
    gemm256<0>(lds, Az, Az, S1 + (size_t)z * kT * kT, 2048, 2048, 2048,
               rr * 256, (rr + tt) * 256, 2048, nullptr);
  } else if (bid < 512) {  // M = emb @ w_w (256 x 1024, K=2048)
    const int m = bid - 508;
    gemm256<0>(lds, embbf, wwT, Mbf, 2048, 2048, 1024, 0, m * 256, 2048, nullptr);
  } else {  // quarters: qj = 0..79; parent s = 124 + qj/4, K-slice ks = qj&3
    const int qj = bid - 512;
    const int s = 124 + (qj >> 2), ks = qj & 3;
    const int z = s / 36;
    int tt = s % 36, rr = 0;
    while (tt >= 8 - rr) { tt -= 8 - rr; rr++; }
    const bf16_t* Az = xbf + (size_t)z * kT * kCIN;
    gemm256<1>(lds, Az + (size_t)(rr * 256) * 2048 + ks * 512,
               Az + (size_t)((rr + tt) * 256) * 2048 + ks * 512,
               S1f + (size_t)qj * 65536, 2048, 2048, 256, 0, 0, 512, nullptr);
  }
}

// ========== dispatch 3: S2 (256 = 1 round) + S1-quarter sum/cast (320) ============
__global__ __launch_bounds__(512, 2) void k_gemm2(const bf16_t* __restrict__ xtphi,
                                                  bf16_t* __restrict__ S2,
                                                  const float* __restrict__ S1f,
                                                  bf16_t* __restrict__ S1) {
  __shared__ bf16_t lds[65536];
  const int bid = blockIdx.x;
  if (bid < 256) {
    const int bm = bid & 7, bn = (bid >> 3) & 7, z = bid >> 6;
    const bf16_t* base = xtphi + (size_t)z * kT * 3072;
    gemm256<0>(lds, base + 1024, base, S2 + (size_t)z * kT * kT, 3072, 3072, 2048,
               bm * 256, bn * 256, 1024, nullptr);
    return;
  }
  // sum 4 K-partials of S1f tile -> bf16 S1.  cb=0..319; 16 blocks per tile.
  const int cb = bid - 256;
  const int t20 = cb >> 4, part = cb & 15;
  const int s = 124 + t20;
  const int z = s / 36;
  int tt = s % 36, rr = 0;
  while (tt >= 8 - rr) { tt -= 8 - rr; rr++; }
  const float* base = S1f + (size_t)(4 * t20) * 65536;
  const int e0 = part * 4096 + threadIdx.x * 8;
  f32x4 lo = *(const f32x4*)(base + e0) ;
  f32x4 hi = *(const f32x4*)(base + e0 + 4);
#pragma unroll
  for (int ks = 1; ks < 4; ks++) {
    const float* p = base + (size_t)ks * 65536 + e0;
    f32x4 l2 = *(const f32x4*)p, h2 = *(const f32x4*)(p + 4);
#pragma unroll
    for (int k = 0; k < 4; k++) { lo[k] += l2[k]; hi[k] += h2[k]; }
  }
  const int r = e0 >> 8, c = e0 & 255;
  bf16x8 o;
#pragma unroll
  for (int k = 0; k < 4; k++) { o[k] = (bf16_t)lo[k]; o[4 + k] = (bf16_t)hi[k]; }
  *(bf16x8*)(S1 + (size_t)z * kT * kT + (size_t)(rr * 256 + r) * kT + (rr + tt) * 256 + c) = o;
}

// ====== dispatch 4: mirror S1 (1984) + xg-transpose (2048), 256-thread blocks =====
__global__ __launch_bounds__(256) void k_util(bf16_t* __restrict__ S1,
                                              const bf16_t* __restrict__ xtphi,
                                              bf16_t* __restrict__ xgT) {
  __shared__ bf16_t tile[64 * 66];
  const int bid = blockIdx.x;
  const size_t T2 = (size_t)kT * kT;
  if (bid < 1984) {  // mirror S1 upper -> lower (64x64 tiles, p>q)
    int z = bid / 496, t = bid % 496, qq = 0;
    while (t >= 31 - qq) { t -= 31 - qq; qq++; }
    int p = qq + 1 + t;
    const size_t base = (size_t)z * T2;
#pragma unroll
    for (int k = 0; k < 16; k++) {
      int e = k * 256 + threadIdx.x;
      int r = e >> 6, c = e & 63;
      tile[r * 66 + c] = S1[base + (size_t)(qq * 64 + r) * kT + p * 64 + c];
    }
    __syncthreads();
#pragma unroll
    for (int k = 0; k < 16; k++) {
      int e = k * 256 + threadIdx.x;
      int r = e >> 6, c = e & 63;
      S1[base + (size_t)(p * 64 + r) * kT + qq * 64 + c] = tile[c * 66 + r];
    }
  } else {  // xgT[z](h,t) from xg slice of xtphi
    int j = bid - 1984;
    int hb = j & 15, tb2 = (j >> 4) & 31, z = j >> 9;
#pragma unroll
    for (int k = 0; k < 16; k++) {
      int e = k * 256 + threadIdx.x;
      int r = e >> 6, c = e & 63;  // r: t, c: h
      tile[r * 66 + c] = xtphi[(size_t)(z * kT + tb2 * 64 + r) * 3072 + 2048 + hb * 64 + c];
    }
    __syncthreads();
#pragma unroll
    for (int k = 0; k < 16; k++) {
      int e = k * 256 + threadIdx.x;
      int r = e >> 6, c = e & 63;  // r: h, c: t
      xgT[(size_t)z * kHID * kT + (size_t)(hb * 64 + r) * kT + tb2 * 64 + c] = tile[c * 66 + r];
    }
  }
}

// ============ dispatch 5: moca — wave-per-row, register-resident ==================
__global__ __launch_bounds__(256) void k_moca(const bf16_t* __restrict__ S1,
                                              const bf16_t* __restrict__ S2,
                                              bf16_t* __restrict__ dst,
                                              const float* __restrict__ rou_w,
                                              const float* __restrict__ rou_b) {
  const int wv = threadIdx.x >> 6, lane = threadIdx.x & 63;
  const int t = blockIdx.x * 4 + wv, b = blockIdx.y;
  const size_t T2 = (size_t)kT * kT;
  const bf16_t* src = (b < 2) ? S1 : S2;
  const int pb = (b < 2) ? 2 * b : 2 * (b - 2);
  const bf16_t* rA = src + (size_t)pb * T2 + (size_t)t * kT;
  const bf16_t* rB = rA + T2;

  float va[32], vb[32];
#pragma unroll
  for (int c = 0; c < 4; c++) {
    bf16x8 a  = *(const bf16x8*)(rA + c * 512 + lane * 8);
    bf16x8 bb = *(const bf16x8*)(rB + c * 512 + lane * 8);
#pragma unroll
    for (int k = 0; k < 8; k++) { va[c * 8 + k] = (float)a[k]; vb[c * 8 + k] = (float)bb[k]; }
  }
  auto wmax = [](float v) {
#pragma unroll
    for (int o = 32; o > 0; o >>= 1) v = fmaxf(v, __shfl_xor(v, o, 64));
    return v;
  };
  auto wsum = [](float v) {
#pragma unroll
    for (int o = 32; o > 0; o >>= 1) v += __shfl_xor(v, o, 64);
    return v;
  };

  float m = -1e30f, s;
#pragma unroll
  for (int j = 0; j < 32; j++) m = fmaxf(m, va[j]);
  m = wmax(m); s = 0.f;
#pragma unroll
  for (int j = 0; j < 32; j++) { va[j] = __expf(va[j] - m); s += va[j]; }
  const float invA = 1.f / wsum(s);

  m = -1e30f;
#pragma unroll
  for (int j = 0; j < 32; j++) m = fmaxf(m, vb[j]);
  m = wmax(m); s = 0.f;
#pragma unroll
  for (int j = 0; j < 32; j++) { vb[j] = __expf(vb[j] - m); s += vb[j]; }
  const float invB = 1.f / wsum(s);

  const float r0 = rou_w[0], r1 = rou_w[1], rb2 = rou_b[0];
#pragma unroll
  for (int j = 0; j < 32; j++) va[j] = r0 * va[j] * invA + r1 * vb[j] * invB + rb2;

  m = -1e30f;
#pragma unroll
  for (int j = 0; j < 32; j++) m = fmaxf(m, va[j]);
  m = wmax(m); s = 0.f;
#pragma unroll
  for (int j = 0; j < 32; j++) { va[j] = __expf(va[j] - m); s += va[j]; }
  const float invC = 1.f / wsum(s);

  bf16_t* o = dst + (size_t)b * T2 + (size_t)t * kT;
#pragma unroll
  for (int c = 0; c < 4; c++) {
    bf16x8 ov;
#pragma unroll
    for (int k = 0; k < 8; k++) ov[k] = (bf16_t)(va[c * 8 + k] * invC);
    *(bf16x8*)(o + c * 512 + lane * 8) = ov;
  }
}

// ================= dispatch 6: mocab -> mocaT (batched TxT transpose) =============
__global__ __launch_bounds__(256) void k_mocaT(const bf16_t* __restrict__ in,
                                               bf16_t* __restrict__ out) {
  __shared__ bf16_t tile[64 * 66];
  size_t base = (size_t)blockIdx.z * kT * kT;
  int r0 = blockIdx.y * 64, c0 = blockIdx.x * 64;
#pragma unroll
  for (int k = 0; k < 16; k++) {
    int e = k * 256 + threadIdx.x;
    int r = e >> 6, c = e & 63;
    tile[r * 66 + c] = in[base + (size_t)(r0 + r) * kT + c0 + c];
  }
  __syncthreads();
#pragma unroll
  for (int k = 0; k < 16; k++) {
    int e = k * 256 + threadIdx.x;
    int r = e >> 6, c = e & 63;
    out[base + (size_t)(c0 + r) * kT + r0 + c] = tile[c * 66 + r];
  }
}

// ====== dispatch 7: yT GEMM (128) + x@emb^T split-K4 atomic (128) = 256 blocks ====
__global__ __launch_bounds__(512, 2) void k_tail1(const bf16_t* __restrict__ mocaT,
                                                  const bf16_t* __restrict__ xgT,
                                                  bf16_t* __restrict__ yT,
                                                  const bf16_t* __restrict__ xbf,
                                                  const bf16_t* __restrict__ embbf,
                                                  float* __restrict__ out,
                                                  const float* __restrict__ biase) {
  __shared__ bf16_t lds[65536];
  const int bid = blockIdx.x;
  if (bid < 128) {  // yT[z] = mocaT[z] @ xgT[z]^T (2048 x 1024, K=2048)
    const int bm = bid & 7, bn = (bid >> 3) & 3, z = bid >> 5;
    gemm256<0>(lds, mocaT + (size_t)z * kT * kT, xgT + (size_t)z * kHID * kT,
               yT + (size_t)z * kT * kHID, 2048, 2048, 1024,
               bm * 256, bn * 256, 2048, nullptr);
  } else {  // out += x @ emb^T (K=512 slices), + biase on slice 0
    const int r = bid - 128;
    const int bm = r & 31, ks = r >> 5;
    gemm256<2>(lds, xbf + ks * 512, embbf + ks * 512, out, 2048, 2048, 256,
               bm * 256, 0, 512, ks == 0 ? biase : nullptr);
  }
}

// ================= dispatch 8: out += yT @ M^T split-K4 atomic (128) ==============
__global__ __launch_bounds__(512, 2) void k_tail2(const bf16_t* __restrict__ yT,
                                                  const bf16_t* __restrict__ Mbf,
                                                  float* __restrict__ out) {
  __shared__ bf16_t lds[65536];
  const int bid = blockIdx.x;
  const int bm = bid & 31, ks = bid >> 5;
  gemm256<2>(lds, yT + ks * 256, Mbf + ks * 256, out, 1024, 1024, 256,
             bm * 256, 0, 256, nullptr);
}

extern "C" void kernel_launch(void* const* d_in, const int* in_sizes, int n_in,
                              void* d_out, int out_size, void* d_ws, size_t ws_size,
                              hipStream_t stream) {
  const float* x       = (const float*)d_in[0];
  const float* theta_w = (const float*)d_in[1];
  const float* theta_b = (const float*)d_in[2];
  const float* phi_w   = (const float*)d_in[3];
  const float* phi_b   = (const float*)d_in[4];
  const float* g_w     = (const float*)d_in[5];
  const float* g_b     = (const float*)d_in[6];
  const float* rou_w   = (const float*)d_in[7];
  const float* rou_b   = (const float*)d_in[8];
  const float* w_w     = (const float*)d_in[9];
  const float* w_b     = (const float*)d_in[10];
  const float* emb_w   = (const float*)d_in[11];
  const float* emb_b   = (const float*)d_in[12];
  float* out = (float*)d_out;

  char* ws = (char*)d_ws;
  size_t off = 0;
  auto alloc = [&](size_t bytes) -> char* {
    off = (off + 255) & ~(size_t)255;
    char* p = ws + off;
    off += bytes;
    return p;
  };

  const size_t BT = (size_t)kB * kT;   // 8192
  const size_t T2 = (size_t)kT * kT;   // 4M

  bf16_t* xbf   = (bf16_t*)alloc(BT * kCIN * 2);               // 33.5 MB
  bf16_t* wqkv  = (bf16_t*)alloc((size_t)3 * kHID * kCIN * 2); // 12.6 MB
  bf16_t* embbf = (bf16_t*)alloc((size_t)kEMB * kCIN * 2);     // 1.0 MB
  bf16_t* wwT   = (bf16_t*)alloc((size_t)kHID * kCIN * 2);     // 4.2 MB
  bf16_t* xtphi = (bf16_t*)alloc(BT * 3072 * 2);               // 50.3 MB [xt|xphi|xg]
  bf16_t* xgT   = (bf16_t*)alloc((size_t)kB * kHID * kT * 2);  // 16.8 MB
  bf16_t* mocab = (bf16_t*)alloc((size_t)kB * T2 * 2);         // 33.5 MB
  bf16_t* Mbf   = (bf16_t*)alloc((size_t)kEMB * kHID * 2);     // 0.5 MB
  float*  biase = (float*)alloc((size_t)kEMB * 4);
  float*  bqkv  = (float*)alloc((size_t)3072 * 4);
  bf16_t* S1    = (bf16_t*)alloc((size_t)kB * T2 * 2);         // 33.5 MB
  bf16_t* S2    = (bf16_t*)alloc((size_t)kB * T2 * 2);         // 33.5 MB
  // aliases over dead regions:
  bf16_t* mocaT = (bf16_t*)xtphi;  // xtphi dead after k_gemm2 + k_util(xgT)
  bf16_t* yT    = (bf16_t*)S2;     // S2 dead after k_moca (16.8 <= 33.5)
  float*  S1f   = (float*)mocab;   // 80*65536*4 = 21 MB <= 33.5; mocab written in k_moca

  // 1: prep (casts + wwT + bias_e + bqkv + zero(out))
  k_prep<<<dim3(25868), 256, 0, stream>>>(x, theta_w, phi_w, g_w, emb_w, w_w, w_b,
                                          emb_b, theta_b, phi_b, g_b,
                                          xbf, wqkv, embbf, wwT, biase, bqkv, out);
  // 2: QKV + S1-tri + M (512 fulls = 2 exact rounds) + 80 S1 split-K quarters
  k_mega1<<<dim3(592), 512, 0, stream>>>(xbf, wqkv, embbf, wwT, xtphi, S1, Mbf,
                                         bqkv, S1f);
  // 3: S2 (256 = 1 round) + S1-quarter sum/cast (320 backfill)
  k_gemm2<<<dim3(576), 512, 0, stream>>>(xtphi, S2, S1f, S1);
  // 4: mirror(S1) + xgT
  k_util<<<dim3(4032), 256, 0, stream>>>(S1, xtphi, xgT);
  // 5: moca (both passes, wave-per-row)
  k_moca<<<dim3(kT / 4, kB), 256, 0, stream>>>(S1, S2, mocab, rou_w, rou_b);
  // 6: mocaT (overwrites dead xtphi)
  k_mocaT<<<dim3(32, 32, kB), 256, 0, stream>>>(mocab, mocaT);
  // 7: yT GEMM (over dead S2) + x@emb^T split-K atomic
  k_tail1<<<dim3(256), 512, 0, stream>>>(mocaT, xgT, yT, xbf, embbf, out, biase);
  // 8: out += yT @ M^T split-K atomic
  k_tail2<<<dim3(128), 512, 0, stream>>>(yT, Mbf, out);
}

// Round 7
// 416.704 us; speedup vs baseline: 1.3251x; 1.0948x over previous
//
#include <hip/hip_runtime.h>
#include <hip/hip_bf16.h>

constexpr int kB   = 4;
constexpr int kT   = 2048;
constexpr int kCIN = 2048;
constexpr int kHID = 1024;
constexpr int kEMB = 256;

typedef __bf16 bf16_t;
typedef __bf16 bf16x8 __attribute__((ext_vector_type(8)));
typedef __bf16 bf16x4 __attribute__((ext_vector_type(4)));
typedef float  f32x4  __attribute__((ext_vector_type(4)));

// async global->LDS 16B/lane (LDS dest = wave-uniform base + lane*16)
__device__ __forceinline__ void gll16(const void* g, void* l) {
  auto lp = reinterpret_cast<__attribute__((address_space(3))) uint32_t*>(
      reinterpret_cast<uintptr_t>(l));
  __builtin_amdgcn_global_load_lds(static_cast<const uint32_t*>(g), lp, 16, 0, 0);
}

#define MFMA_BF16 __builtin_amdgcn_mfma_f32_16x16x32_bf16

// ================= 256x256 8-phase double-buffered GEMM core ======================
// C[m,n] = sum_k A[m,k]*B[n,k] (+biasN).  512 thr = 8 waves, BK=64, Klen%64==0,
// Klen>=512.  LDS 128 KiB dbuf.  Core frozen since r6 (schedule variants r1-r5 all
// ~equal; MFMA floor is 2048cy/K-tile at 16cy/MFMA per SIMD; observed 5520).
// MODE 0: bf16 store; MODE 1: f32 plain store.  (atomics eliminated pipeline-wide)
template <int MODE>
__device__ __forceinline__ void gemm256(bf16_t* lds, const bf16_t* A, const bf16_t* B,
                                        void* Cv, int lda, int ldb, int ldc,
                                        int m0, int n0, int Klen, const float* biasN) {
  const int tid  = threadIdx.x;
  const int lane = tid & 63, wv = tid >> 6;
  const int wm = wv & 1, wn = wv >> 1;
  const int lm = lane & 15, q = lane >> 4;
  const int l8 = lane >> 3;
  const int slot = (lane & 7) ^ l8;   // pre-swizzled source 16B-slot

  bf16_t* const sA = lds;
  bf16_t* const sB = lds + 32768;

  int aoff[4], boff[4];
#pragma unroll
  for (int cc = 0; cc < 4; cc++) {
    const int ra = cc * 64 + wv * 8 + l8;
    aoff[cc] = ra * lda;
    const int nb = ((ra >> 5) & 3) * 64 + (ra >> 7) * 32 + (ra & 31);  // B permuted
    boff[cc] = nb * ldb;
  }
  const bf16_t* const Ab = A + (size_t)m0 * lda + slot * 8;
  const bf16_t* const Bb = B + (size_t)n0 * ldb + slot * 8;

  const int x0 = ((q ^ (lm & 7)) << 3);
  const int x1 = (((q + 4) ^ (lm & 7)) << 3);

#define STAGE_A(T, H)                                                         \
  {                                                                           \
    bf16_t* dst_ = sA + (((T) & 1) << 14);                                    \
    const bf16_t* src_ = Ab + ((T) << 6);                                     \
    gll16(src_ + aoff[(H)], dst_ + ((H) << 12) + (wv << 9));                  \
    gll16(src_ + aoff[2 + (H)], dst_ + ((2 + (H)) << 12) + (wv << 9));        \
  }
#define STAGE_B(T, G)                                                         \
  {                                                                           \
    bf16_t* dst_ = sB + (((T) & 1) << 14);                                    \
    const bf16_t* src_ = Bb + ((T) << 6);                                     \
    gll16(src_ + boff[2 * (G)], dst_ + ((2 * (G)) << 12) + (wv << 9));        \
    gll16(src_ + boff[2 * (G) + 1], dst_ + ((2 * (G) + 1) << 12) + (wv << 9));\
  }
#define READ_A(BUF, H)                                                        \
  _Pragma("unroll") for (int i = 0; i < 4; i++) {                             \
    const bf16_t* p_ = (BUF) + ((wm * 128 + (H) * 64 + i * 16 + lm) << 6);    \
    af[i][0] = *(const bf16x8*)(p_ + x0);                                     \
    af[i][1] = *(const bf16x8*)(p_ + x1);                                     \
  }
#define READ_B(BF, BUF, G)                                                    \
  _Pragma("unroll") for (int j2 = 0; j2 < 2; j2++) {                          \
    const bf16_t* p_ = (BUF) + (((G) * 128 + wn * 32 + j2 * 16 + lm) << 6);   \
    BF[j2][0] = *(const bf16x8*)(p_ + x0);                                    \
    BF[j2][1] = *(const bf16x8*)(p_ + x1);                                    \
  }
#define QUAD(H, G, BF)                                                        \
  _Pragma("unroll") for (int i2 = 0; i2 < 4; i2++)                            \
  _Pragma("unroll") for (int j2 = 0; j2 < 2; j2++)                            \
  _Pragma("unroll") for (int kk = 0; kk < 2; kk++)                            \
    acc[(H) * 4 + i2][(G) * 2 + j2] = MFMA_BF16(                              \
        af[i2][kk], BF[j2][kk], acc[(H) * 4 + i2][(G) * 2 + j2], 0, 0, 0);
#define MFMA_OPEN()                                                           \
  asm volatile("s_waitcnt lgkmcnt(0)" ::: "memory");                          \
  __builtin_amdgcn_s_setprio(1);
#define MFMA_CLOSE() __builtin_amdgcn_s_setprio(0);

  f32x4 acc[8][4];
#pragma unroll
  for (int i = 0; i < 8; i++)
#pragma unroll
    for (int j = 0; j < 4; j++)
#pragma unroll
      for (int r = 0; r < 4; r++) acc[i][j][r] = 0.f;

  const int nt = Klen >> 6;

  STAGE_A(0, 0) STAGE_B(0, 0) STAGE_B(0, 1) STAGE_A(0, 1)
  STAGE_A(1, 0) STAGE_B(1, 0) STAGE_B(1, 1) STAGE_A(1, 1)
  asm volatile("s_waitcnt vmcnt(8)" ::: "memory");
  __builtin_amdgcn_s_barrier();

  bf16x8 af[4][2], bf0[2][2], bf1[2][2];
  for (int t = 0; t < nt; t++) {
    bf16_t* const a = sA + ((t & 1) << 14);
    bf16_t* const b = sB + ((t & 1) << 14);
    const bool pf = (t + 2) < nt;
    READ_A(a, 0)
    READ_B(bf0, b, 0)
    asm volatile("s_waitcnt lgkmcnt(8)" ::: "memory");
    __builtin_amdgcn_s_barrier();
    MFMA_OPEN()
    QUAD(0, 0, bf0)
    MFMA_CLOSE()
    __builtin_amdgcn_s_barrier();
    READ_B(bf1, b, 1)
    if (pf) STAGE_A(t + 2, 0)
    __builtin_amdgcn_s_barrier();
    MFMA_OPEN()
    QUAD(0, 1, bf1)
    MFMA_CLOSE()
    __builtin_amdgcn_s_barrier();
    READ_A(a, 1)
    if (pf) STAGE_B(t + 2, 0)
    __builtin_amdgcn_s_barrier();
    MFMA_OPEN()
    QUAD(1, 1, bf1)
    MFMA_CLOSE()
    __builtin_amdgcn_s_barrier();
    if (pf) { STAGE_B(t + 2, 1) STAGE_A(t + 2, 1) }
    __builtin_amdgcn_s_barrier();
    __builtin_amdgcn_s_setprio(1);
    QUAD(1, 0, bf0)
    __builtin_amdgcn_s_setprio(0);
    if (pf)
      asm volatile("s_waitcnt vmcnt(8)" ::: "memory");
    else if (t + 1 < nt)
      asm volatile("s_waitcnt vmcnt(0)" ::: "memory");
    __builtin_amdgcn_s_barrier();
  }

#pragma unroll
  for (int i = 0; i < 8; i++) {
    const int gm = m0 + wm * 128 + (i >> 2) * 64 + (i & 3) * 16 + q * 4;
#pragma unroll
    for (int j = 0; j < 4; j++) {
      const int gn = n0 + wn * 64 + j * 16 + lm;
      const float bn_ = biasN ? biasN[gn] : 0.f;
#pragma unroll
      for (int r = 0; r < 4; r++) {
        const float v = acc[i][j][r] + bn_;
        const size_t idx = (size_t)(gm + r) * ldc + gn;
        if (MODE == 0) ((bf16_t*)Cv)[idx] = (bf16_t)v;
        else           ((float*)Cv)[idx] = v;
      }
    }
  }
#undef STAGE_A
#undef STAGE_B
#undef READ_A
#undef READ_B
#undef QUAD
#undef MFMA_OPEN
#undef MFMA_CLOSE
}

// mirror-late predicate: the 20 S1 tiles computed via split-K (s>=124, all z==3)
__device__ __forceinline__ bool mirror_is_late(int z, int qq, int p) {
  const int R = qq >> 2, C = p >> 2;
  const int local = 8 * R - (R * (R - 1)) / 2 + (C - R);
  return (z == 3) && (local >= 16);
}

// ================= dispatch 1: prep (casts + wwT + biases) ========================
__global__ __launch_bounds__(256) void k_prep(const float* __restrict__ x,
                                              const float* __restrict__ th,
                                              const float* __restrict__ ph,
                                              const float* __restrict__ g,
                                              const float* __restrict__ emb,
                                              const float* __restrict__ w_w,
                                              const float* __restrict__ w_b,
                                              const float* __restrict__ emb_b,
                                              const float* __restrict__ tb,
                                              const float* __restrict__ pb,
                                              const float* __restrict__ gb,
                                              bf16_t* __restrict__ xbf,
                                              bf16_t* __restrict__ wqkv,
                                              bf16_t* __restrict__ embbf,
                                              bf16_t* __restrict__ wwT,
                                              float* __restrict__ biase,
                                              float* __restrict__ bqkv) {
  __shared__ float tile[64 * 66];
  const int b = blockIdx.x;
  if (b < 23040) {  // casts
    const float* in; bf16_t* o; long i;
    if (b < 16384)      { in = x;   o = xbf;                            i = (long)b * 256 + threadIdx.x; }
    else if (b < 18432) { in = th;  o = wqkv;                           i = (long)(b - 16384) * 256 + threadIdx.x; }
    else if (b < 20480) { in = ph;  o = wqkv + (size_t)kHID * kCIN;     i = (long)(b - 18432) * 256 + threadIdx.x; }
    else if (b < 22528) { in = g;   o = wqkv + (size_t)2 * kHID * kCIN; i = (long)(b - 20480) * 256 + threadIdx.x; }
    else                { in = emb; o = embbf;                          i = (long)(b - 22528) * 256 + threadIdx.x; }
    float4 v = ((const float4*)in)[i];
    bf16x4 ov;
    ov[0] = (bf16_t)v.x; ov[1] = (bf16_t)v.y; ov[2] = (bf16_t)v.z; ov[3] = (bf16_t)v.w;
    ((bf16x4*)o)[i] = ov;
  } else if (b < 23552) {  // w_w (CIN,HID) -> wwT (HID,CIN)
    int j = b - 23040;
    int h0 = (j & 15) * 64, c0 = (j >> 4) * 64;
#pragma unroll
    for (int k = 0; k < 16; k++) {
      int e = k * 256 + threadIdx.x;
      int r = e >> 6, c = e & 63;
      tile[r * 66 + c] = w_w[(size_t)(c0 + r) * kHID + h0 + c];
    }
    __syncthreads();
#pragma unroll
    for (int k = 0; k < 16; k++) {
      int e = k * 256 + threadIdx.x;
      int r = e >> 6, c = e & 63;
      wwT[(size_t)(h0 + r) * kCIN + c0 + c] = (bf16_t)tile[c * 66 + r];
    }
  } else if (b < 23808) {  // bias_e = emb @ w_b + emb_b
    int e = b - 23552;
    float acc = 0.f;
    for (int c = threadIdx.x; c < kCIN; c += 256)
      acc += emb[(size_t)e * kCIN + c] * w_b[c];
#pragma unroll
    for (int o = 32; o > 0; o >>= 1) acc += __shfl_xor(acc, o, 64);
    __syncthreads();
    if ((threadIdx.x & 63) == 0) tile[threadIdx.x >> 6] = acc;
    __syncthreads();
    if (threadIdx.x == 0) biase[e] = tile[0] + tile[1] + tile[2] + tile[3] + emb_b[e];
  } else {  // concat biases -> bqkv[3072]
    int i = (b - 23808) * 256 + threadIdx.x;
    if (i < 3072)
      bqkv[i] = i < 1024 ? tb[i] : (i < 2048 ? pb[i - 1024] : gb[i - 2048]);
  }
}

// ====== dispatch 2: 512 full jobs (2 exact rounds) + 80 S1 split-K quarters =======
__global__ __launch_bounds__(512, 2) void k_mega1(const bf16_t* __restrict__ xbf,
                                                  const bf16_t* __restrict__ wqkv,
                                                  const bf16_t* __restrict__ embbf,
                                                  const bf16_t* __restrict__ wwT,
                                                  bf16_t* __restrict__ xtphi,
                                                  bf16_t* __restrict__ S1,
                                                  bf16_t* __restrict__ Mbf,
                                                  const float* __restrict__ bqkv,
                                                  float* __restrict__ S1f) {
  __shared__ bf16_t lds[65536];
  const int bid = blockIdx.x;
  if (bid < 384) {  // xtphi = x @ wqkv^T + bqkv (8192 x 3072, K=2048)
    const int bm = bid & 31, bn = bid >> 5;
    gemm256<0>(lds, xbf, wqkv, xtphi, 2048, 2048, 3072,
               bm * 256, bn * 256, 2048, bqkv);
  } else if (bid < 508) {  // S1 full tiles: s = 0..123
    int s = bid - 384;
    const int z = s / 36;
    int tt = s % 36, rr = 0;
    while (tt >= 8 - rr) { tt -= 8 - rr; rr++; }
    const bf16_t* Az = xbf + (size_t)z * kT * kCIN;
    gemm256<0>(lds, Az, Az, S1 + (size_t)z * kT * kT, 2048, 2048, 2048,
               rr * 256, (rr + tt) * 256, 2048, nullptr);
  } else if (bid < 512) {  // M = emb @ w_w (256 x 1024, K=2048)
    const int m = bid - 508;
    gemm256<0>(lds, embbf, wwT, Mbf, 2048, 2048, 1024, 0, m * 256, 2048, nullptr);
  } else {  // S1 quarters: qj = 0..79; s = 124 + qj/4, K-slice ks = qj&3 (f32 partials)
    const int qj = bid - 512;
    const int s = 124 + (qj >> 2), ks = qj & 3;
    const int z = s / 36;
    int tt = s % 36, rr = 0;
    while (tt >= 8 - rr) { tt -= 8 - rr; rr++; }
    const bf16_t* Az = xbf + (size_t)z * kT * kCIN;
    gemm256<1>(lds, Az + (size_t)(rr * 256) * 2048 + ks * 512,
               Az + (size_t)((rr + tt) * 256) * 2048 + ks * 512,
               S1f + (size_t)qj * 65536, 2048, 2048, 256, 0, 0, 512, nullptr);
  }
}

// ====== dispatch 3: S2(256) + W-quarters(64) + S1casts(320) + mirror-nonlate ======
// W[z][e,t] = sum_h M[e,h]*xg[z][h,t]; xg[h,t] lives at xtphi[z*T+t][2048+h]
// (h-contiguous) so B = xtphi rows t, NO transpose needed.  64 jobs K=512 -> Wf.
__global__ __launch_bounds__(512, 2) void k_gemm2(const bf16_t* __restrict__ xtphi,
                                                  bf16_t* __restrict__ S2,
                                                  const float* __restrict__ S1f,
                                                  bf16_t* __restrict__ S1,
                                                  const bf16_t* __restrict__ Mbf,
                                                  float* __restrict__ Wf) {
  __shared__ bf16_t lds[65536];
  const int bid = blockIdx.x;
  if (bid < 256) {  // S2[z] = xphi[z] @ xt[z]^T (K=1024)
    const int bm = bid & 7, bn = (bid >> 3) & 7, z = bid >> 6;
    const bf16_t* base = xtphi + (size_t)z * kT * 3072;
    gemm256<0>(lds, base + 1024, base, S2 + (size_t)z * kT * kT, 3072, 3072, 2048,
               bm * 256, bn * 256, 1024, nullptr);
  } else if (bid < 320) {  // W quarters: wj = 0..63; tile = wj&31 (z*8+nt), ks = wj>>5
    const int wj = bid - 256;
    const int tle = wj & 31, ks = wj >> 5;
    const int z = tle >> 3, ntile = tle & 7;
    gemm256<1>(lds, Mbf + ks * 512,
               xtphi + (size_t)(z * kT + ntile * 256) * 3072 + 2048 + ks * 512,
               Wf + (size_t)(ks * 32 + tle) * 65536, 1024, 3072, 256, 0, 0, 512,
               nullptr);
  } else if (bid < 640) {  // sum 4 K-partials of late S1 tiles -> bf16
    const int cb = bid - 320;
    const int t20 = cb >> 4, part = cb & 15;
    const int s = 124 + t20;
    const int z = s / 36;
    int tt = s % 36, rr = 0;
    while (tt >= 8 - rr) { tt -= 8 - rr; rr++; }
    const float* base = S1f + (size_t)(4 * t20) * 65536;
    const int e0 = part * 4096 + threadIdx.x * 8;
    f32x4 lo = *(const f32x4*)(base + e0);
    f32x4 hi = *(const f32x4*)(base + e0 + 4);
#pragma unroll
    for (int ks = 1; ks < 4; ks++) {
      const float* p = base + (size_t)ks * 65536 + e0;
      f32x4 l2 = *(const f32x4*)p, h2 = *(const f32x4*)(p + 4);
#pragma unroll
      for (int k = 0; k < 4; k++) { lo[k] += l2[k]; hi[k] += h2[k]; }
    }
    const int r = e0 >> 8, c = e0 & 255;
    bf16x8 o;
#pragma unroll
    for (int k = 0; k < 4; k++) { o[k] = (bf16_t)lo[k]; o[4 + k] = (bf16_t)hi[k]; }
    *(bf16x8*)(S1 + (size_t)z * kT * kT + (size_t)(rr * 256 + r) * kT + (rr + tt) * 256 + c) = o;
  } else {  // mirror S1 upper->lower, NON-late 64x64 blocks only (late done in D4)
    int j = bid - 640;
    int z = j / 496, t = j % 496, qq = 0;
    while (t >= 31 - qq) { t -= 31 - qq; qq++; }
    int p = qq + 1 + t;
    if (mirror_is_late(z, qq, p)) return;
    bf16_t* tile = lds;  // 64*66 bf16
    const size_t base = (size_t)z * kT * kT;
#pragma unroll
    for (int k = 0; k < 8; k++) {
      int e = k * 512 + threadIdx.x;
      int r = e >> 6, c = e & 63;
      tile[r * 66 + c] = S1[base + (size_t)(qq * 64 + r) * kT + p * 64 + c];
    }
    __syncthreads();
#pragma unroll
    for (int k = 0; k < 8; k++) {
      int e = k * 512 + threadIdx.x;
      int r = e >> 6, c = e & 63;
      S1[base + (size_t)(p * 64 + r) * kT + qq * 64 + c] = tile[c * 66 + r];
    }
  }
}

// ====== dispatch 4: mirror-late (270 of 1984) + W combine (Wf 2 slices -> bf16) ===
__global__ __launch_bounds__(256) void k_util2(bf16_t* __restrict__ S1,
                                               const float* __restrict__ Wf,
                                               bf16_t* __restrict__ W) {
  __shared__ bf16_t tile[64 * 66];
  const int bid = blockIdx.x;
  if (bid < 1984) {
    int j = bid;
    int z = j / 496, t = j % 496, qq = 0;
    while (t >= 31 - qq) { t -= 31 - qq; qq++; }
    int p = qq + 1 + t;
    if (!mirror_is_late(z, qq, p)) return;
    const size_t base = (size_t)z * kT * kT;
#pragma unroll
    for (int k = 0; k < 16; k++) {
      int e = k * 256 + threadIdx.x;
      int r = e >> 6, c = e & 63;
      tile[r * 66 + c] = S1[base + (size_t)(qq * 64 + r) * kT + p * 64 + c];
    }
    __syncthreads();
#pragma unroll
    for (int k = 0; k < 16; k++) {
      int e = k * 256 + threadIdx.x;
      int r = e >> 6, c = e & 63;
      S1[base + (size_t)(p * 64 + r) * kT + qq * 64 + c] = tile[c * 66 + r];
    }
  } else {  // W combine: 1024 blocks x 2048 elems
    const long i = (long)(bid - 1984) * 2048 + threadIdx.x * 8;
    const int tle = (int)(i >> 16), w = (int)(i & 65535);
    const float* a = Wf + (size_t)tle * 65536 + w;
    const float* b = a + (size_t)32 * 65536;
    f32x4 lo = *(const f32x4*)a, hi = *(const f32x4*)(a + 4);
    f32x4 l2 = *(const f32x4*)b, h2 = *(const f32x4*)(b + 4);
    const int e = w >> 8, sl = w & 255;
    bf16x8 o;
#pragma unroll
    for (int k = 0; k < 4; k++) {
      o[k]     = (bf16_t)(lo[k] + l2[k]);
      o[4 + k] = (bf16_t)(hi[k] + h2[k]);
    }
    *(bf16x8*)(W + (size_t)(tle >> 3) * kEMB * kT + (size_t)e * kT + (tle & 7) * 256 + sl) = o;
  }
}

// ============ dispatch 5: moca — wave-per-row, register-resident ==================
__global__ __launch_bounds__(256) void k_moca(const bf16_t* __restrict__ S1,
                                              const bf16_t* __restrict__ S2,
                                              bf16_t* __restrict__ dst,
                                              const float* __restrict__ rou_w,
                                              const float* __restrict__ rou_b) {
  const int wv = threadIdx.x >> 6, lane = threadIdx.x & 63;
  const int t = blockIdx.x * 4 + wv, b = blockIdx.y;
  const size_t T2 = (size_t)kT * kT;
  const bf16_t* src = (b < 2) ? S1 : S2;
  const int pb = (b < 2) ? 2 * b : 2 * (b - 2);
  const bf16_t* rA = src + (size_t)pb * T2 + (size_t)t * kT;
  const bf16_t* rB = rA + T2;

  float va[32], vb[32];
#pragma unroll
  for (int c = 0; c < 4; c++) {
    bf16x8 a  = *(const bf16x8*)(rA + c * 512 + lane * 8);
    bf16x8 bb = *(const bf16x8*)(rB + c * 512 + lane * 8);
#pragma unroll
    for (int k = 0; k < 8; k++) { va[c * 8 + k] = (float)a[k]; vb[c * 8 + k] = (float)bb[k]; }
  }
  auto wmax = [](float v) {
#pragma unroll
    for (int o = 32; o > 0; o >>= 1) v = fmaxf(v, __shfl_xor(v, o, 64));
    return v;
  };
  auto wsum = [](float v) {
#pragma unroll
    for (int o = 32; o > 0; o >>= 1) v += __shfl_xor(v, o, 64);
    return v;
  };

  float m = -1e30f, s;
#pragma unroll
  for (int j = 0; j < 32; j++) m = fmaxf(m, va[j]);
  m = wmax(m); s = 0.f;
#pragma unroll
  for (int j = 0; j < 32; j++) { va[j] = __expf(va[j] - m); s += va[j]; }
  const float invA = 1.f / wsum(s);

  m = -1e30f;
#pragma unroll
  for (int j = 0; j < 32; j++) m = fmaxf(m, vb[j]);
  m = wmax(m); s = 0.f;
#pragma unroll
  for (int j = 0; j < 32; j++) { vb[j] = __expf(vb[j] - m); s += vb[j]; }
  const float invB = 1.f / wsum(s);

  const float r0 = rou_w[0], r1 = rou_w[1], rb2 = rou_b[0];
#pragma unroll
  for (int j = 0; j < 32; j++) va[j] = r0 * va[j] * invA + r1 * vb[j] * invB + rb2;

  m = -1e30f;
#pragma unroll
  for (int j = 0; j < 32; j++) m = fmaxf(m, va[j]);
  m = wmax(m); s = 0.f;
#pragma unroll
  for (int j = 0; j < 32; j++) { va[j] = __expf(va[j] - m); s += va[j]; }
  const float invC = 1.f / wsum(s);

  bf16_t* o = dst + (size_t)b * T2 + (size_t)t * kT;
#pragma unroll
  for (int c = 0; c < 4; c++) {
    bf16x8 ov;
#pragma unroll
    for (int k = 0; k < 8; k++) ov[k] = (bf16_t)(va[c * 8 + k] * invC);
    *(bf16x8*)(o + c * 512 + lane * 8) = ov;
  }
}

// ================= dispatch 6: mocab -> mocaT (batched TxT transpose) =============
__global__ __launch_bounds__(256) void k_mocaT(const bf16_t* __restrict__ in,
                                               bf16_t* __restrict__ out) {
  __shared__ bf16_t tile[64 * 66];
  size_t base = (size_t)blockIdx.z * kT * kT;
  int r0 = blockIdx.y * 64, c0 = blockIdx.x * 64;
#pragma unroll
  for (int k = 0; k < 16; k++) {
    int e = k * 256 + threadIdx.x;
    int r = e >> 6, c = e & 63;
    tile[r * 66 + c] = in[base + (size_t)(r0 + r) * kT + c0 + c];
  }
  __syncthreads();
#pragma unroll
  for (int k = 0; k < 16; k++) {
    int e = k * 256 + threadIdx.x;
    int r = e >> 6, c = e & 63;
    out[base + (size_t)(c0 + r) * kT + r0 + c] = tile[c * 66 + r];
  }
}

// ====== dispatch 7: out slices — 256 uniform K=512 jobs (1 quarter-round) =========
// out[t,e] = sum_t' mocaT[z][t,t']*W[z][e,t']  (K=2048, slices 0-3)
//          + sum_c  x[t,c]*emb[e,c]            (K=2048, slices 4-7)
// each job: one 256-row tile (m=0..31) x one K=512 slice -> f32 partial outf[ks].
__global__ __launch_bounds__(512, 2) void k_outq(const bf16_t* __restrict__ mocaT,
                                                 const bf16_t* __restrict__ W,
                                                 const bf16_t* __restrict__ xbf,
                                                 const bf16_t* __restrict__ embbf,
                                                 float* __restrict__ outf) {
  __shared__ bf16_t lds[65536];
  const int bid = blockIdx.x;
  const int m = bid & 31, ks = bid >> 5;
  float* Cv = outf + (size_t)ks * 2097152 + (size_t)m * 65536;
  if (ks < 4) {
    const int z = m >> 3;
    gemm256<1>(lds,
               mocaT + (size_t)z * kT * kT + (size_t)((m & 7) * 256) * kT + ks * 512,
               W + (size_t)z * kEMB * kT + ks * 512,
               Cv, 2048, 2048, 256, 0, 0, 512, nullptr);
  } else {
    gemm256<1>(lds,
               xbf + (size_t)(m * 256) * kCIN + (ks - 4) * 512,
               embbf + (ks - 4) * 512,
               Cv, 2048, 2048, 256, 0, 0, 512, nullptr);
  }
}

// ================= dispatch 8: out = sum of 8 partials + biase ====================
__global__ __launch_bounds__(256) void k_fin(const float* __restrict__ outf,
                                             const float* __restrict__ biase,
                                             float* __restrict__ out) {
  const long i = (long)blockIdx.x * 2048 + threadIdx.x * 8;
  const int e0 = (int)(i & 255);
  f32x4 lo = {0.f, 0.f, 0.f, 0.f}, hi = {0.f, 0.f, 0.f, 0.f};
#pragma unroll
  for (int ks = 0; ks < 8; ks++) {
    const float* p = outf + (size_t)ks * 2097152 + i;
    f32x4 l2 = *(const f32x4*)p, h2 = *(const f32x4*)(p + 4);
#pragma unroll
    for (int k = 0; k < 4; k++) { lo[k] += l2[k]; hi[k] += h2[k]; }
  }
#pragma unroll
  for (int k = 0; k < 4; k++) {
    lo[k] += biase[e0 + k];
    hi[k] += biase[e0 + 4 + k];
  }
  *(f32x4*)(out + i) = lo;
  *(f32x4*)(out + i + 4) = hi;
}

extern "C" void kernel_launch(void* const* d_in, const int* in_sizes, int n_in,
                              void* d_out, int out_size, void* d_ws, size_t ws_size,
                              hipStream_t stream) {
  const float* x       = (const float*)d_in[0];
  const float* theta_w = (const float*)d_in[1];
  const float* theta_b = (const float*)d_in[2];
  const float* phi_w   = (const float*)d_in[3];
  const float* phi_b   = (const float*)d_in[4];
  const float* g_w     = (const float*)d_in[5];
  const float* g_b     = (const float*)d_in[6];
  const float* rou_w   = (const float*)d_in[7];
  const float* rou_b   = (const float*)d_in[8];
  const float* w_w     = (const float*)d_in[9];
  const float* w_b     = (const float*)d_in[10];
  const float* emb_w   = (const float*)d_in[11];
  const float* emb_b   = (const float*)d_in[12];
  float* out = (float*)d_out;

  char* ws = (char*)d_ws;
  size_t off = 0;
  auto alloc = [&](size_t bytes) -> char* {
    off = (off + 255) & ~(size_t)255;
    char* p = ws + off;
    off += bytes;
    return p;
  };

  const size_t BT = (size_t)kB * kT;   // 8192
  const size_t T2 = (size_t)kT * kT;   // 4M

  bf16_t* xbf   = (bf16_t*)alloc(BT * kCIN * 2);               // 33.5 MB
  bf16_t* wqkv  = (bf16_t*)alloc((size_t)3 * kHID * kCIN * 2); // 12.6 MB
  bf16_t* embbf = (bf16_t*)alloc((size_t)kEMB * kCIN * 2);     // 1.0 MB
  bf16_t* wwT   = (bf16_t*)alloc((size_t)kHID * kCIN * 2);     // 4.2 MB
  bf16_t* xtphi = (bf16_t*)alloc(BT * 3072 * 2);               // 50.3 MB [xt|xphi|xg]
  float*  Wf    = (float*)alloc((size_t)64 * 65536 * 4);       // 16.8 MB (W partials)
  bf16_t* mocab = (bf16_t*)alloc((size_t)kB * T2 * 2);         // 33.5 MB
  bf16_t* Mbf   = (bf16_t*)alloc((size_t)kEMB * kHID * 2);     // 0.5 MB
  bf16_t* W     = (bf16_t*)alloc((size_t)kB * kEMB * kT * 2);  // 4.2 MB
  float*  biase = (float*)alloc((size_t)kEMB * 4);
  float*  bqkv  = (float*)alloc((size_t)3072 * 4);
  bf16_t* S1    = (bf16_t*)alloc((size_t)kB * T2 * 2);         // 33.5 MB
  bf16_t* S2    = (bf16_t*)alloc((size_t)kB * T2 * 2);         // 33.5 MB (contig after S1)
  // aliases over dead regions:
  bf16_t* mocaT = (bf16_t*)xtphi;  // xtphi dead after k_gemm2 (S2 + W reads)
  float*  S1f   = (float*)mocab;   // read in k_gemm2; mocab written later (k_moca)
  float*  outf  = (float*)S1;      // 8 x 8.4 MB = 67.1 MB = S1+S2 (dead after k_moca)

  // 1: prep (casts + wwT + bias_e + bqkv)
  k_prep<<<dim3(23820), 256, 0, stream>>>(x, theta_w, phi_w, g_w, emb_w, w_w, w_b,
                                          emb_b, theta_b, phi_b, g_b,
                                          xbf, wqkv, embbf, wwT, biase, bqkv);
  // 2: QKV + S1-tri + M (512 fulls = 2 exact rounds) + 80 S1 split-K quarters
  k_mega1<<<dim3(592), 512, 0, stream>>>(xbf, wqkv, embbf, wwT, xtphi, S1, Mbf,
                                         bqkv, S1f);
  // 3: S2 + W-quarters + S1 casts + mirror(non-late)
  k_gemm2<<<dim3(2624), 512, 0, stream>>>(xtphi, S2, S1f, S1, Mbf, Wf);
  // 4: mirror(late, 270 active) + W combine
  k_util2<<<dim3(3008), 256, 0, stream>>>(S1, Wf, W);
  // 5: moca (both passes, wave-per-row)
  k_moca<<<dim3(kT / 4, kB), 256, 0, stream>>>(S1, S2, mocab, rou_w, rou_b);
  // 6: mocaT (overwrites dead xtphi)
  k_mocaT<<<dim3(32, 32, kB), 256, 0, stream>>>(mocab, mocaT);
  // 7: out slices (256 uniform K=512 jobs -> f32 partials over dead S1+S2)
  k_outq<<<dim3(256), 512, 0, stream>>>(mocaT, W, xbf, embbf, outf);
  // 8: out = sum partials + biase
  k_fin<<<dim3(1024), 256, 0, stream>>>(outf, biase, out);
}

// Round 8
// 410.841 us; speedup vs baseline: 1.3440x; 1.0143x over previous
//
#include <hip/hip_runtime.h>
#include <hip/hip_bf16.h>

constexpr int kB   = 4;
constexpr int kT   = 2048;
constexpr int kCIN = 2048;
constexpr int kHID = 1024;
constexpr int kEMB = 256;

typedef __bf16 bf16_t;
typedef __bf16 bf16x8 __attribute__((ext_vector_type(8)));
typedef __bf16 bf16x4 __attribute__((ext_vector_type(4)));
typedef float  f32x4  __attribute__((ext_vector_type(4)));

// async global->LDS 16B/lane (LDS dest = wave-uniform base + lane*16)
__device__ __forceinline__ void gll16(const void* g, void* l) {
  auto lp = reinterpret_cast<__attribute__((address_space(3))) uint32_t*>(
      reinterpret_cast<uintptr_t>(l));
  __builtin_amdgcn_global_load_lds(static_cast<const uint32_t*>(g), lp, 16, 0, 0);
}

#define MFMA_BF16 __builtin_amdgcn_mfma_f32_16x16x32_bf16

// ================= 256x256 8-phase double-buffered GEMM core (FROZEN r6) ==========
// C[m,n] = sum_k A[m,k]*B[n,k] (+biasN).  512 thr = 8 waves, BK=64, Klen%64==0.
// MODE 0: bf16 store; MODE 1: f32 plain store.
template <int MODE>
__device__ __forceinline__ void gemm256(bf16_t* lds, const bf16_t* A, const bf16_t* B,
                                        void* Cv, int lda, int ldb, int ldc,
                                        int m0, int n0, int Klen, const float* biasN) {
  const int tid  = threadIdx.x;
  const int lane = tid & 63, wv = tid >> 6;
  const int wm = wv & 1, wn = wv >> 1;
  const int lm = lane & 15, q = lane >> 4;
  const int l8 = lane >> 3;
  const int slot = (lane & 7) ^ l8;

  bf16_t* const sA = lds;
  bf16_t* const sB = lds + 32768;

  int aoff[4], boff[4];
#pragma unroll
  for (int cc = 0; cc < 4; cc++) {
    const int ra = cc * 64 + wv * 8 + l8;
    aoff[cc] = ra * lda;
    const int nb = ((ra >> 5) & 3) * 64 + (ra >> 7) * 32 + (ra & 31);
    boff[cc] = nb * ldb;
  }
  const bf16_t* const Ab = A + (size_t)m0 * lda + slot * 8;
  const bf16_t* const Bb = B + (size_t)n0 * ldb + slot * 8;

  const int x0 = ((q ^ (lm & 7)) << 3);
  const int x1 = (((q + 4) ^ (lm & 7)) << 3);

#define STAGE_A(T, H)                                                         \
  {                                                                           \
    bf16_t* dst_ = sA + (((T) & 1) << 14);                                    \
    const bf16_t* src_ = Ab + ((T) << 6);                                     \
    gll16(src_ + aoff[(H)], dst_ + ((H) << 12) + (wv << 9));                  \
    gll16(src_ + aoff[2 + (H)], dst_ + ((2 + (H)) << 12) + (wv << 9));        \
  }
#define STAGE_B(T, G)                                                         \
  {                                                                           \
    bf16_t* dst_ = sB + (((T) & 1) << 14);                                    \
    const bf16_t* src_ = Bb + ((T) << 6);                                     \
    gll16(src_ + boff[2 * (G)], dst_ + ((2 * (G)) << 12) + (wv << 9));        \
    gll16(src_ + boff[2 * (G) + 1], dst_ + ((2 * (G) + 1) << 12) + (wv << 9));\
  }
#define READ_A(BUF, H)                                                        \
  _Pragma("unroll") for (int i = 0; i < 4; i++) {                             \
    const bf16_t* p_ = (BUF) + ((wm * 128 + (H) * 64 + i * 16 + lm) << 6);    \
    af[i][0] = *(const bf16x8*)(p_ + x0);                                     \
    af[i][1] = *(const bf16x8*)(p_ + x1);                                     \
  }
#define READ_B(BF, BUF, G)                                                    \
  _Pragma("unroll") for (int j2 = 0; j2 < 2; j2++) {                          \
    const bf16_t* p_ = (BUF) + (((G) * 128 + wn * 32 + j2 * 16 + lm) << 6);   \
    BF[j2][0] = *(const bf16x8*)(p_ + x0);                                    \
    BF[j2][1] = *(const bf16x8*)(p_ + x1);                                    \
  }
#define QUAD(H, G, BF)                                                        \
  _Pragma("unroll") for (int i2 = 0; i2 < 4; i2++)                            \
  _Pragma("unroll") for (int j2 = 0; j2 < 2; j2++)                            \
  _Pragma("unroll") for (int kk = 0; kk < 2; kk++)                            \
    acc[(H) * 4 + i2][(G) * 2 + j2] = MFMA_BF16(                              \
        af[i2][kk], BF[j2][kk], acc[(H) * 4 + i2][(G) * 2 + j2], 0, 0, 0);
#define MFMA_OPEN()                                                           \
  asm volatile("s_waitcnt lgkmcnt(0)" ::: "memory");                          \
  __builtin_amdgcn_s_setprio(1);
#define MFMA_CLOSE() __builtin_amdgcn_s_setprio(0);

  f32x4 acc[8][4];
#pragma unroll
  for (int i = 0; i < 8; i++)
#pragma unroll
    for (int j = 0; j < 4; j++)
#pragma unroll
      for (int r = 0; r < 4; r++) acc[i][j][r] = 0.f;

  const int nt = Klen >> 6;

  STAGE_A(0, 0) STAGE_B(0, 0) STAGE_B(0, 1) STAGE_A(0, 1)
  STAGE_A(1, 0) STAGE_B(1, 0) STAGE_B(1, 1) STAGE_A(1, 1)
  asm volatile("s_waitcnt vmcnt(8)" ::: "memory");
  __builtin_amdgcn_s_barrier();

  bf16x8 af[4][2], bf0[2][2], bf1[2][2];
  for (int t = 0; t < nt; t++) {
    bf16_t* const a = sA + ((t & 1) << 14);
    bf16_t* const b = sB + ((t & 1) << 14);
    const bool pf = (t + 2) < nt;
    READ_A(a, 0)
    READ_B(bf0, b, 0)
    asm volatile("s_waitcnt lgkmcnt(8)" ::: "memory");
    __builtin_amdgcn_s_barrier();
    MFMA_OPEN()
    QUAD(0, 0, bf0)
    MFMA_CLOSE()
    __builtin_amdgcn_s_barrier();
    READ_B(bf1, b, 1)
    if (pf) STAGE_A(t + 2, 0)
    __builtin_amdgcn_s_barrier();
    MFMA_OPEN()
    QUAD(0, 1, bf1)
    MFMA_CLOSE()
    __builtin_amdgcn_s_barrier();
    READ_A(a, 1)
    if (pf) STAGE_B(t + 2, 0)
    __builtin_amdgcn_s_barrier();
    MFMA_OPEN()
    QUAD(1, 1, bf1)
    MFMA_CLOSE()
    __builtin_amdgcn_s_barrier();
    if (pf) { STAGE_B(t + 2, 1) STAGE_A(t + 2, 1) }
    __builtin_amdgcn_s_barrier();
    __builtin_amdgcn_s_setprio(1);
    QUAD(1, 0, bf0)
    __builtin_amdgcn_s_setprio(0);
    if (pf)
      asm volatile("s_waitcnt vmcnt(8)" ::: "memory");
    else if (t + 1 < nt)
      asm volatile("s_waitcnt vmcnt(0)" ::: "memory");
    __builtin_amdgcn_s_barrier();
  }

#pragma unroll
  for (int i = 0; i < 8; i++) {
    const int gm = m0 + wm * 128 + (i >> 2) * 64 + (i & 3) * 16 + q * 4;
#pragma unroll
    for (int j = 0; j < 4; j++) {
      const int gn = n0 + wn * 64 + j * 16 + lm;
      const float bn_ = biasN ? biasN[gn] : 0.f;
#pragma unroll
      for (int r = 0; r < 4; r++) {
        const float v = acc[i][j][r] + bn_;
        const size_t idx = (size_t)(gm + r) * ldc + gn;
        if (MODE == 0) ((bf16_t*)Cv)[idx] = (bf16_t)v;
        else           ((float*)Cv)[idx] = v;
      }
    }
  }
#undef STAGE_A
#undef STAGE_B
#undef READ_A
#undef READ_B
#undef QUAD
#undef MFMA_OPEN
#undef MFMA_CLOSE
}

// mirror-late predicate: the 20 S1 tiles computed via split-K (z==3, local>=16)
__device__ __forceinline__ bool mirror_is_late(int z, int qq, int p) {
  const int R = qq >> 2, C = p >> 2;
  const int local = 8 * R - (R * (R - 1)) / 2 + (C - R);
  return (z == 3) && (local >= 16);
}

// ================= dispatch 1: prep (casts + wwT + biases) ========================
__global__ __launch_bounds__(256) void k_prep(const float* __restrict__ x,
                                              const float* __restrict__ th,
                                              const float* __restrict__ ph,
                                              const float* __restrict__ g,
                                              const float* __restrict__ emb,
                                              const float* __restrict__ w_w,
                                              const float* __restrict__ w_b,
                                              const float* __restrict__ emb_b,
                                              const float* __restrict__ tb,
                                              const float* __restrict__ pb,
                                              const float* __restrict__ gb,
                                              bf16_t* __restrict__ xbf,
                                              bf16_t* __restrict__ wqkv,
                                              bf16_t* __restrict__ embbf,
                                              bf16_t* __restrict__ wwT,
                                              float* __restrict__ biase,
                                              float* __restrict__ bqkv) {
  __shared__ float tile[64 * 66];
  const int b = blockIdx.x;
  if (b < 23040) {  // casts
    const float* in; bf16_t* o; long i;
    if (b < 16384)      { in = x;   o = xbf;                            i = (long)b * 256 + threadIdx.x; }
    else if (b < 18432) { in = th;  o = wqkv;                           i = (long)(b - 16384) * 256 + threadIdx.x; }
    else if (b < 20480) { in = ph;  o = wqkv + (size_t)kHID * kCIN;     i = (long)(b - 18432) * 256 + threadIdx.x; }
    else if (b < 22528) { in = g;   o = wqkv + (size_t)2 * kHID * kCIN; i = (long)(b - 20480) * 256 + threadIdx.x; }
    else                { in = emb; o = embbf;                          i = (long)(b - 22528) * 256 + threadIdx.x; }
    float4 v = ((const float4*)in)[i];
    bf16x4 ov;
    ov[0] = (bf16_t)v.x; ov[1] = (bf16_t)v.y; ov[2] = (bf16_t)v.z; ov[3] = (bf16_t)v.w;
    ((bf16x4*)o)[i] = ov;
  } else if (b < 23552) {  // w_w (CIN,HID) -> wwT (HID,CIN)
    int j = b - 23040;
    int h0 = (j & 15) * 64, c0 = (j >> 4) * 64;
#pragma unroll
    for (int k = 0; k < 16; k++) {
      int e = k * 256 + threadIdx.x;
      int r = e >> 6, c = e & 63;
      tile[r * 66 + c] = w_w[(size_t)(c0 + r) * kHID + h0 + c];
    }
    __syncthreads();
#pragma unroll
    for (int k = 0; k < 16; k++) {
      int e = k * 256 + threadIdx.x;
      int r = e >> 6, c = e & 63;
      wwT[(size_t)(h0 + r) * kCIN + c0 + c] = (bf16_t)tile[c * 66 + r];
    }
  } else if (b < 23808) {  // bias_e = emb @ w_b + emb_b
    int e = b - 23552;
    float acc = 0.f;
    for (int c = threadIdx.x; c < kCIN; c += 256)
      acc += emb[(size_t)e * kCIN + c] * w_b[c];
#pragma unroll
    for (int o = 32; o > 0; o >>= 1) acc += __shfl_xor(acc, o, 64);
    __syncthreads();
    if ((threadIdx.x & 63) == 0) tile[threadIdx.x >> 6] = acc;
    __syncthreads();
    if (threadIdx.x == 0) biase[e] = tile[0] + tile[1] + tile[2] + tile[3] + emb_b[e];
  } else {  // concat biases -> bqkv[3072]
    int i = (b - 23808) * 256 + threadIdx.x;
    if (i < 3072)
      bqkv[i] = i < 1024 ? tb[i] : (i < 2048 ? pb[i - 1024] : gb[i - 2048]);
  }
}

// ========== dispatch 2: QKV(384) + S1-full(124) + M(4) = 512 = 2 EXACT rounds =====
__global__ __launch_bounds__(512, 2) void k_mega1(const bf16_t* __restrict__ xbf,
                                                  const bf16_t* __restrict__ wqkv,
                                                  const bf16_t* __restrict__ embbf,
                                                  const bf16_t* __restrict__ wwT,
                                                  bf16_t* __restrict__ xtphi,
                                                  bf16_t* __restrict__ S1,
                                                  bf16_t* __restrict__ Mbf,
                                                  const float* __restrict__ bqkv) {
  __shared__ bf16_t lds[65536];
  const int bid = blockIdx.x;
  if (bid < 384) {  // xtphi = x @ wqkv^T + bqkv (8192 x 3072, K=2048)
    const int bm = bid & 31, bn = bid >> 5;
    gemm256<0>(lds, xbf, wqkv, xtphi, 2048, 2048, 3072,
               bm * 256, bn * 256, 2048, bqkv);
  } else if (bid < 508) {  // S1 full tiles: s = 0..123
    int s = bid - 384;
    const int z = s / 36;
    int tt = s % 36, rr = 0;
    while (tt >= 8 - rr) { tt -= 8 - rr; rr++; }
    const bf16_t* Az = xbf + (size_t)z * kT * kCIN;
    gemm256<0>(lds, Az, Az, S1 + (size_t)z * kT * kT, 2048, 2048, 2048,
               rr * 256, (rr + tt) * 256, 2048, nullptr);
  } else {  // M = emb @ w_w (256 x 1024, K=2048)
    const int m = bid - 508;
    gemm256<0>(lds, embbf, wwT, Mbf, 2048, 2048, 1024, 0, m * 256, 2048, nullptr);
  }
}

// ====== dispatch 3: S2(256, round 1) + W-quarters(64) + S1-quarters(80) ===========
// round 2 = 144 short jobs (K=512) on the CUs freed by finishing S2 jobs.
__global__ __launch_bounds__(512, 2) void k_gemm2(const bf16_t* __restrict__ xtphi,
                                                  bf16_t* __restrict__ S2,
                                                  const bf16_t* __restrict__ Mbf,
                                                  float* __restrict__ Wf,
                                                  const bf16_t* __restrict__ xbf,
                                                  float* __restrict__ S1f) {
  __shared__ bf16_t lds[65536];
  const int bid = blockIdx.x;
  if (bid < 256) {  // S2[z] = xphi[z] @ xt[z]^T (K=1024)
    const int bm = bid & 7, bn = (bid >> 3) & 7, z = bid >> 6;
    const bf16_t* base = xtphi + (size_t)z * kT * 3072;
    gemm256<0>(lds, base + 1024, base, S2 + (size_t)z * kT * kT, 3072, 3072, 2048,
               bm * 256, bn * 256, 1024, nullptr);
  } else if (bid < 320) {  // W quarters: wj = 0..63; tile = wj&31, ks = wj>>5
    const int wj = bid - 256;
    const int tle = wj & 31, ks = wj >> 5;
    const int z = tle >> 3, ntile = tle & 7;
    gemm256<1>(lds, Mbf + ks * 512,
               xtphi + (size_t)(z * kT + ntile * 256) * 3072 + 2048 + ks * 512,
               Wf + (size_t)(ks * 32 + tle) * 65536, 1024, 3072, 256, 0, 0, 512,
               nullptr);
  } else {  // S1 quarters: qj = 0..79; s = 124 + qj/4, K-slice ks = qj&3
    const int qj = bid - 320;
    const int s = 124 + (qj >> 2), ks = qj & 3;
    const int z = s / 36;
    int tt = s % 36, rr = 0;
    while (tt >= 8 - rr) { tt -= 8 - rr; rr++; }
    const bf16_t* Az = xbf + (size_t)z * kT * kCIN;
    gemm256<1>(lds, Az + (size_t)(rr * 256) * 2048 + ks * 512,
               Az + (size_t)((rr + tt) * 256) * 2048 + ks * 512,
               S1f + (size_t)qj * 65536, 2048, 2048, 256, 0, 0, 512, nullptr);
  }
}

// ====== dispatch 4 (256-thr, high-occ): S1 cast+sym-transpose(320) + ==============
// ====== mirror-nonlate(1984 gated) + W-combine(1024) = 3328 blocks ================
__global__ __launch_bounds__(256) void k_util2(bf16_t* __restrict__ S1,
                                               const float* __restrict__ S1f,
                                               const float* __restrict__ Wf,
                                               bf16_t* __restrict__ W) {
  __shared__ bf16_t tile[64 * 66];
  const int bid = blockIdx.x;
  const size_t T2 = (size_t)kT * kT;
  if (bid < 320) {  // late-tile 64x64 sub-block: sum 4 partials -> upper + lower^T
    const int t20 = bid >> 4, sb = bid & 15;
    const int sr = sb >> 2, sc = sb & 3;
    const int s = 124 + t20;
    const int z = s / 36;
    int tt = s % 36, rr = 0;
    while (tt >= 8 - rr) { tt -= 8 - rr; rr++; }
    const int cc = rr + tt;
    if (tt == 0 && sr > sc) return;  // covered by partner sub-block's transpose
    const int r = threadIdx.x >> 2, c0 = (threadIdx.x & 3) << 4;
    const float* base = S1f + (size_t)(4 * t20) * 65536 +
                        (size_t)(sr * 64 + r) * 256 + sc * 64 + c0;
    float v[16];
#pragma unroll
    for (int k = 0; k < 16; k++) v[k] = 0.f;
#pragma unroll
    for (int ks = 0; ks < 4; ks++) {
      const float* p = base + (size_t)ks * 65536;
#pragma unroll
      for (int q4 = 0; q4 < 4; q4++) {
        f32x4 t4 = *(const f32x4*)(p + q4 * 4);
#pragma unroll
        for (int k = 0; k < 4; k++) v[q4 * 4 + k] += t4[k];
      }
    }
    bf16x8 o0, o1;
#pragma unroll
    for (int k = 0; k < 8; k++) { o0[k] = (bf16_t)v[k]; o1[k] = (bf16_t)v[8 + k]; }
    const size_t zb = (size_t)z * T2;
    bf16_t* up = S1 + zb + (size_t)(rr * 256 + sr * 64 + r) * kT + cc * 256 + sc * 64 + c0;
    *(bf16x8*)up = o0;
    *(bf16x8*)(up + 8) = o1;
    if (tt == 0 && sr == sc) return;  // globally diagonal sub-block: no mirror
#pragma unroll
    for (int k = 0; k < 8; k++) {
      tile[r * 66 + c0 + k]     = o0[k];
      tile[r * 66 + c0 + 8 + k] = o1[k];
    }
    __syncthreads();
    bf16x8 w0, w1;
#pragma unroll
    for (int k = 0; k < 8; k++) {
      w0[k] = tile[(c0 + k) * 66 + r];
      w1[k] = tile[(c0 + 8 + k) * 66 + r];
    }
    bf16_t* lo = S1 + zb + (size_t)(cc * 256 + sc * 64 + r) * kT + rr * 256 + sr * 64 + c0;
    *(bf16x8*)lo = w0;
    *(bf16x8*)(lo + 8) = w1;
  } else if (bid < 2304) {  // mirror S1 upper->lower, NON-late 64x64 blocks
    int j = bid - 320;
    int z = j / 496, t = j % 496, qq = 0;
    while (t >= 31 - qq) { t -= 31 - qq; qq++; }
    int p = qq + 1 + t;
    if (mirror_is_late(z, qq, p)) return;
    const size_t base = (size_t)z * T2;
#pragma unroll
    for (int k = 0; k < 16; k++) {
      int e = k * 256 + threadIdx.x;
      int r = e >> 6, c = e & 63;
      tile[r * 66 + c] = S1[base + (size_t)(qq * 64 + r) * kT + p * 64 + c];
    }
    __syncthreads();
#pragma unroll
    for (int k = 0; k < 16; k++) {
      int e = k * 256 + threadIdx.x;
      int r = e >> 6, c = e & 63;
      S1[base + (size_t)(p * 64 + r) * kT + qq * 64 + c] = tile[c * 66 + r];
    }
  } else {  // W combine: 1024 blocks x 2048 elems
    const long i = (long)(bid - 2304) * 2048 + threadIdx.x * 8;
    const int tle = (int)(i >> 16), w = (int)(i & 65535);
    const float* a = Wf + (size_t)tle * 65536 + w;
    const float* b = a + (size_t)32 * 65536;
    f32x4 lo = *(const f32x4*)a, hi = *(const f32x4*)(a + 4);
    f32x4 l2 = *(const f32x4*)b, h2 = *(const f32x4*)(b + 4);
    const int e = w >> 8, sl = w & 255;
    bf16x8 o;
#pragma unroll
    for (int k = 0; k < 4; k++) {
      o[k]     = (bf16_t)(lo[k] + l2[k]);
      o[4 + k] = (bf16_t)(hi[k] + h2[k]);
    }
    *(bf16x8*)(W + (size_t)(tle >> 3) * kEMB * kT + (size_t)e * kT + (tle & 7) * 256 + sl) = o;
  }
}

// ============ dispatch 5: moca — wave-per-row, register-resident ==================
__global__ __launch_bounds__(256) void k_moca(const bf16_t* __restrict__ S1,
                                              const bf16_t* __restrict__ S2,
                                              bf16_t* __restrict__ dst,
                                              const float* __restrict__ rou_w,
                                              const float* __restrict__ rou_b) {
  const int wv = threadIdx.x >> 6, lane = threadIdx.x & 63;
  const int t = blockIdx.x * 4 + wv, b = blockIdx.y;
  const size_t T2 = (size_t)kT * kT;
  const bf16_t* src = (b < 2) ? S1 : S2;
  const int pb = (b < 2) ? 2 * b : 2 * (b - 2);
  const bf16_t* rA = src + (size_t)pb * T2 + (size_t)t * kT;
  const bf16_t* rB = rA + T2;

  float va[32], vb[32];
#pragma unroll
  for (int c = 0; c < 4; c++) {
    bf16x8 a  = *(const bf16x8*)(rA + c * 512 + lane * 8);
    bf16x8 bb = *(const bf16x8*)(rB + c * 512 + lane * 8);
#pragma unroll
    for (int k = 0; k < 8; k++) { va[c * 8 + k] = (float)a[k]; vb[c * 8 + k] = (float)bb[k]; }
  }
  auto wmax = [](float v) {
#pragma unroll
    for (int o = 32; o > 0; o >>= 1) v = fmaxf(v, __shfl_xor(v, o, 64));
    return v;
  };
  auto wsum = [](float v) {
#pragma unroll
    for (int o = 32; o > 0; o >>= 1) v += __shfl_xor(v, o, 64);
    return v;
  };

  float m = -1e30f, s;
#pragma unroll
  for (int j = 0; j < 32; j++) m = fmaxf(m, va[j]);
  m = wmax(m); s = 0.f;
#pragma unroll
  for (int j = 0; j < 32; j++) { va[j] = __expf(va[j] - m); s += va[j]; }
  const float invA = 1.f / wsum(s);

  m = -1e30f;
#pragma unroll
  for (int j = 0; j < 32; j++) m = fmaxf(m, vb[j]);
  m = wmax(m); s = 0.f;
#pragma unroll
  for (int j = 0; j < 32; j++) { vb[j] = __expf(vb[j] - m); s += vb[j]; }
  const float invB = 1.f / wsum(s);

  const float r0 = rou_w[0], r1 = rou_w[1], rb2 = rou_b[0];
#pragma unroll
  for (int j = 0; j < 32; j++) va[j] = r0 * va[j] * invA + r1 * vb[j] * invB + rb2;

  m = -1e30f;
#pragma unroll
  for (int j = 0; j < 32; j++) m = fmaxf(m, va[j]);
  m = wmax(m); s = 0.f;
#pragma unroll
  for (int j = 0; j < 32; j++) { va[j] = __expf(va[j] - m); s += va[j]; }
  const float invC = 1.f / wsum(s);

  bf16_t* o = dst + (size_t)b * T2 + (size_t)t * kT;
#pragma unroll
  for (int c = 0; c < 4; c++) {
    bf16x8 ov;
#pragma unroll
    for (int k = 0; k < 8; k++) ov[k] = (bf16_t)(va[c * 8 + k] * invC);
    *(bf16x8*)(o + c * 512 + lane * 8) = ov;
  }
}

// ================= dispatch 6: mocab -> mocaT (batched TxT transpose) =============
__global__ __launch_bounds__(256) void k_mocaT(const bf16_t* __restrict__ in,
                                               bf16_t* __restrict__ out) {
  __shared__ bf16_t tile[64 * 66];
  size_t base = (size_t)blockIdx.z * kT * kT;
  int r0 = blockIdx.y * 64, c0 = blockIdx.x * 64;
#pragma unroll
  for (int k = 0; k < 16; k++) {
    int e = k * 256 + threadIdx.x;
    int r = e >> 6, c = e & 63;
    tile[r * 66 + c] = in[base + (size_t)(r0 + r) * kT + c0 + c];
  }
  __syncthreads();
#pragma unroll
  for (int k = 0; k < 16; k++) {
    int e = k * 256 + threadIdx.x;
    int r = e >> 6, c = e & 63;
    out[base + (size_t)(c0 + r) * kT + r0 + c] = tile[c * 66 + r];
  }
}

// ====== dispatch 7: out slices — 128 jobs K=1024 (4 partial slices total) =========
// slices 0-1: moca^T @ W^T halves; slices 2-3: x @ emb^T halves.
__global__ __launch_bounds__(512, 2) void k_outq(const bf16_t* __restrict__ mocaT,
                                                 const bf16_t* __restrict__ W,
                                                 const bf16_t* __restrict__ xbf,
                                                 const bf16_t* __restrict__ embbf,
                                                 float* __restrict__ outf) {
  __shared__ bf16_t lds[65536];
  const int bid = blockIdx.x;
  if (bid < 64) {
    const int m = bid & 31, kh = bid >> 5;
    const int z = m >> 3;
    gemm256<1>(lds,
               mocaT + (size_t)z * kT * kT + (size_t)((m & 7) * 256) * kT + kh * 1024,
               W + (size_t)z * kEMB * kT + kh * 1024,
               outf + (size_t)kh * 2097152 + (size_t)m * 65536,
               2048, 2048, 256, 0, 0, 1024, nullptr);
  } else {
    const int r = bid - 64;
    const int m = r & 31, kh = r >> 5;
    gemm256<1>(lds,
               xbf + (size_t)(m * 256) * kCIN + kh * 1024,
               embbf + kh * 1024,
               outf + (size_t)(2 + kh) * 2097152 + (size_t)m * 65536,
               2048, 2048, 256, 0, 0, 1024, nullptr);
  }
}

// ================= dispatch 8: out = sum of 4 partials + biase ====================
__global__ __launch_bounds__(256) void k_fin(const float* __restrict__ outf,
                                             const float* __restrict__ biase,
                                             float* __restrict__ out) {
  const long i = (long)blockIdx.x * 2048 + threadIdx.x * 8;
  const int e0 = (int)(i & 255);
  f32x4 lo = {0.f, 0.f, 0.f, 0.f}, hi = {0.f, 0.f, 0.f, 0.f};
#pragma unroll
  for (int ks = 0; ks < 4; ks++) {
    const float* p = outf + (size_t)ks * 2097152 + i;
    f32x4 l2 = *(const f32x4*)p, h2 = *(const f32x4*)(p + 4);
#pragma unroll
    for (int k = 0; k < 4; k++) { lo[k] += l2[k]; hi[k] += h2[k]; }
  }
#pragma unroll
  for (int k = 0; k < 4; k++) {
    lo[k] += biase[e0 + k];
    hi[k] += biase[e0 + 4 + k];
  }
  *(f32x4*)(out + i) = lo;
  *(f32x4*)(out + i + 4) = hi;
}

extern "C" void kernel_launch(void* const* d_in, const int* in_sizes, int n_in,
                              void* d_out, int out_size, void* d_ws, size_t ws_size,
                              hipStream_t stream) {
  const float* x       = (const float*)d_in[0];
  const float* theta_w = (const float*)d_in[1];
  const float* theta_b = (const float*)d_in[2];
  const float* phi_w   = (const float*)d_in[3];
  const float* phi_b   = (const float*)d_in[4];
  const float* g_w     = (const float*)d_in[5];
  const float* g_b     = (const float*)d_in[6];
  const float* rou_w   = (const float*)d_in[7];
  const float* rou_b   = (const float*)d_in[8];
  const float* w_w     = (const float*)d_in[9];
  const float* w_b     = (const float*)d_in[10];
  const float* emb_w   = (const float*)d_in[11];
  const float* emb_b   = (const float*)d_in[12];
  float* out = (float*)d_out;

  char* ws = (char*)d_ws;
  size_t off = 0;
  auto alloc = [&](size_t bytes) -> char* {
    off = (off + 255) & ~(size_t)255;
    char* p = ws + off;
    off += bytes;
    return p;
  };

  const size_t BT = (size_t)kB * kT;   // 8192
  const size_t T2 = (size_t)kT * kT;   // 4M

  bf16_t* xbf   = (bf16_t*)alloc(BT * kCIN * 2);               // 33.5 MB
  bf16_t* wqkv  = (bf16_t*)alloc((size_t)3 * kHID * kCIN * 2); // 12.6 MB
  bf16_t* embbf = (bf16_t*)alloc((size_t)kEMB * kCIN * 2);     // 1.0 MB
  bf16_t* wwT   = (bf16_t*)alloc((size_t)kHID * kCIN * 2);     // 4.2 MB
  bf16_t* xtphi = (bf16_t*)alloc(BT * 3072 * 2);               // 50.3 MB [xt|xphi|xg]
  float*  Wf    = (float*)alloc((size_t)64 * 65536 * 4);       // 16.8 MB (W partials)
  bf16_t* mocab = (bf16_t*)alloc((size_t)kB * T2 * 2);         // 33.5 MB
  bf16_t* Mbf   = (bf16_t*)alloc((size_t)kEMB * kHID * 2);     // 0.5 MB
  bf16_t* W     = (bf16_t*)alloc((size_t)kB * kEMB * kT * 2);  // 4.2 MB
  float*  biase = (float*)alloc((size_t)kEMB * 4);
  float*  bqkv  = (float*)alloc((size_t)3072 * 4);
  bf16_t* S1    = (bf16_t*)alloc((size_t)kB * T2 * 2);         // 33.5 MB
  bf16_t* S2    = (bf16_t*)alloc((size_t)kB * T2 * 2);         // 33.5 MB
  // aliases over dead regions:
  bf16_t* mocaT = (bf16_t*)xtphi;  // xtphi dead after k_gemm2 (S2 + W reads)
  float*  S1f   = (float*)mocab;   // read in k_util2; mocab written later (k_moca)
  float*  outf  = (float*)S1;      // 4 x 8.4 MB = 33.5 MB = S1 (dead after k_moca)

  // 1: prep (casts + wwT + bias_e + bqkv)
  k_prep<<<dim3(23820), 256, 0, stream>>>(x, theta_w, phi_w, g_w, emb_w, w_w, w_b,
                                          emb_b, theta_b, phi_b, g_b,
                                          xbf, wqkv, embbf, wwT, biase, bqkv);
  // 2: QKV + S1-full + M = 512 jobs = 2 exact rounds
  k_mega1<<<dim3(512), 512, 0, stream>>>(xbf, wqkv, embbf, wwT, xtphi, S1, Mbf, bqkv);
  // 3: S2 (round 1) + W-quarters + S1-quarters (round 2)
  k_gemm2<<<dim3(400), 512, 0, stream>>>(xtphi, S2, Mbf, Wf, xbf, S1f);
  // 4: S1 cast+sym-transpose + mirror(non-late) + W combine (high-occ)
  k_util2<<<dim3(3328), 256, 0, stream>>>(S1, S1f, Wf, W);
  // 5: moca (both passes, wave-per-row)
  k_moca<<<dim3(kT / 4, kB), 256, 0, stream>>>(S1, S2, mocab, rou_w, rou_b);
  // 6: mocaT (overwrites dead xtphi)
  k_mocaT<<<dim3(32, 32, kB), 256, 0, stream>>>(mocab, mocaT);
  // 7: out slices (128 K=1024 jobs -> 4 f32 partial slices over dead S1)
  k_outq<<<dim3(128), 512, 0, stream>>>(mocaT, W, xbf, embbf, outf);
  // 8: out = sum partials + biase
  k_fin<<<dim3(1024), 256, 0, stream>>>(outf, biase, out);
}